// Round 11
// baseline (1119.201 us; speedup 1.0000x reference)
//
#include <hip/hip_runtime.h>
#include <math.h>

// Problem constants (fixed by setup_inputs: B=4, D=128, T=8, P=4096)
#define BB 4
#define DD 128
#define TT 8
#define PP 4096
#define KK 10
#define NT 7              // T-1 frame pairs
#define BP (BB*PP)        // 16384 points per frame across batch
#define NQ (NT*BP)        // 114688 total queries
#define NBLK_COS 896
#define QPB 128           // queries per block in cos kernel (NBLK_COS*QPB == NQ)

#define CHUNKS 4
#define CSZ (PP/CHUNKS)   // 1024 candidates per chunk (filter pass)
#define TSZ 256           // tau-subset slice per block: 4 blocks x 256 = 1024-subset
#define FCAP 28           // per-chunk recorded cap (survivors/chunk ~Poi(10))
#define LSTRIDE (FCAP+1)  // LDS row stride (u32) -> conflict-free copy-out

// Workspace layout (bytes). Everything below OFF_IDX aliases the featT
// region (58.7 MB) and is fully consumed by knn_finish BEFORE
// transpose_kernel writes featT (same-stream ordering).
#define OFF_FEATT 0u                 // NQ*DD floats  = 58,720,256 B
#define OFF_PARTV 0u                 // CHUNKS*KK*NQ uints = 18,350,080 B
#define OFF_CAND4 20971520u          // BB*TT*PP float4 = 2,097,152 B
#define OFF_TAU   23068672u          // NQ floats = 458,752 B
#define OFF_FCNT  23527424u          // CHUNKS*NQ uints = 1,835,008 B
#define OFF_FLIST 25362432u          // CHUNKS*FCAP*NQ u16 = 25,690,112 B (ends 51.1 MB)
#define OFF_IDX   58720256u          // NQ*KK ints    =  4,587,520 B
#define OFF_DV    63307776u          // NQ floats     =    458,752 B
#define OFF_NORM  63766528u          // NQ floats     =    458,752 B
#define OFF_SCALE 64225280u          // NT floats (padded to 256)
#define OFF_PART  64225536u          // NBLK_COS floats

// __builtin_amdgcn_cvt_pkrtz returns __fp16 ext_vector_type(2).
typedef __fp16 f16x2 __attribute__((ext_vector_type(2)));
union H2U { f16x2 h; unsigned u; };

// Packed f16 min/max via inline asm (clang promotes elementwise builtins on
// f16 vectors to f32 — round-8 post-mortem).
__device__ __forceinline__ f16x2 pk_min(f16x2 a, f16x2 b) {
  f16x2 d;
  asm("v_pk_min_f16 %0, %1, %2" : "=v"(d) : "v"(a), "v"(b));
  return d;
}
__device__ __forceinline__ f16x2 pk_max(f16x2 a, f16x2 b) {
  f16x2 d;
  asm("v_pk_max_f16 %0, %1, %2" : "=v"(d) : "v"(a), "v"(b));
  return d;
}

// md = |q-c|^2 computed as (xx_q + xx_c) - 2*inner. MUST be the same
// expression in every kernel (bit-identical md values make the threshold
// argument exact).
__device__ __forceinline__ float md_of(const float4 q, const float4 c) {
  float s = q.w + c.w;
  float inner = fmaf(q.x, c.x, fmaf(q.y, c.y, q.z * c.z));
  return fmaf(-2.0f, inner, s);
}

// Packed-f16 "keep 10 smallest" ladder over two independent candidate
// streams (.x / .y). Values are conservative UPPER bounds of md:
// cvt_pkrtz (toward zero = down for positives) then +2 f16-ulps.
__device__ __forceinline__ void ins2(f16x2 (&bv)[KK], float mdA, float mdB) {
  H2U cv;
  cv.h = __builtin_amdgcn_cvt_pkrtz(mdA, mdB);
  cv.u += 0x00020002u;  // +2 ulps up (values small positive; no NaN/ovf)
  bv[KK - 1] = pk_min(bv[KK - 1], cv.h);
#pragma unroll
  for (int i = KK - 1; i > 0; --i) {
    f16x2 lo = pk_min(bv[i - 1], bv[i]);
    f16x2 hi = pk_max(bv[i - 1], bv[i]);
    bv[i - 1] = lo;
    bv[i] = hi;
  }
}
__device__ __forceinline__ void insh(f16x2 (&bv)[KK], f16x2 h) {
  bv[KK - 1] = pk_min(bv[KK - 1], h);
#pragma unroll
  for (int i = KK - 1; i > 0; --i) {
    f16x2 lo = pk_min(bv[i - 1], bv[i]);
    f16x2 hi = pk_max(bv[i - 1], bv[i]);
    bv[i - 1] = lo;
    bv[i] = hi;
  }
}

// f32 keep-10-smallest (values only), branchless.
__device__ __forceinline__ void insf(float (&bv)[KK], float v) {
  bv[KK - 1] = fminf(bv[KK - 1], v);
#pragma unroll
  for (int i = KK - 1; i > 0; --i) {
    float lo = fminf(bv[i - 1], bv[i]);
    float hi = fmaxf(bv[i - 1], bv[i]);
    bv[i - 1] = lo;
    bv[i] = hi;
  }
}

// Exact stable (md,idx) insert: keep 10 smallest, ascending md; strict-<
// entry/bubble over an ascending-j insert stream keeps earlier index on
// ties — exactly jax.lax.top_k's tie rule.
__device__ __forceinline__ void insp(float (&v)[KK], int (&vi)[KK], float md,
                                     int j) {
  bool en = md < v[KK - 1];
  v[KK - 1] = en ? md : v[KK - 1];
  vi[KK - 1] = en ? j : vi[KK - 1];
#pragma unroll
  for (int i = KK - 1; i > 0; --i) {
    bool sw = v[i] < v[i - 1];
    float tv = sw ? v[i - 1] : v[i];
    v[i - 1] = sw ? v[i] : v[i - 1];
    v[i] = tv;
    int ti = sw ? vi[i - 1] : vi[i];
    vi[i - 1] = sw ? vi[i] : vi[i - 1];
    vi[i] = ti;
  }
}

// ---------------------------------------------------------------------------
// Kernel P: precompute (x,y,z,xx) per point.
// ---------------------------------------------------------------------------
__global__ __launch_bounds__(256) void prep_cand(
    const float* __restrict__ pts4, float4* __restrict__ cand4) {
  const int i = blockIdx.x * 256 + threadIdx.x;  // over BB*TT*PP
  float4 v = ((const float4*)pts4)[i];
  v.w = fmaf(v.x, v.x, fmaf(v.y, v.y, v.z * v.z));
  cand4[i] = v;
}

// ---------------------------------------------------------------------------
// Kernel A1: f16 upper bounds of top-10 md over a 1024-candidate SUBSET
// (candidates [0,1024) of the slice; 4 blocks x 256 cands). Validity: the
// 10th-smallest of ANY >=10-element subset upper-bounds the global 10th.
// ---------------------------------------------------------------------------
__global__ __launch_bounds__(256) void knn_thr_partial(
    const float4* __restrict__ cand4, unsigned* __restrict__ part) {
  const int qg = blockIdx.x >> 2;  // query group 0..15
  const int c = blockIdx.x & 3;    // subset slice 0..3
  const int b = blockIdx.y, t = blockIdx.z;
  const float4* __restrict__ src = cand4 + ((size_t)(b * TT + t) * PP);
  const float4* __restrict__ ch = src + c * TSZ;  // subset slice [c*256,..)

  const int p = qg * 256 + threadIdx.x;
  const float4 q = src[p];

  H2U inf2;
  inf2.u = 0x7C007C00u;
  f16x2 l1[KK], l2[KK];
#pragma unroll
  for (int i = 0; i < KK; ++i) { l1[i] = inf2.h; l2[i] = inf2.h; }

  for (int j = 0; j < TSZ; j += 4) {
    float4 c0 = ch[j], c1 = ch[j + 1], c2 = ch[j + 2], c3 = ch[j + 3];
    float md0 = md_of(q, c0);
    float md1 = md_of(q, c1);
    float md2 = md_of(q, c2);
    float md3 = md_of(q, c3);
    ins2(l1, md0, md1);
    ins2(l2, md2, md3);
  }
  // merge stream-pairs: l1 <- per-component union top-10 (streams of 64 >= 10)
#pragma unroll
  for (int r = 0; r < KK; ++r) insh(l1, l2[r]);

  const size_t qid = (size_t)(t * BB + b) * PP + p;
#pragma unroll
  for (int r = 0; r < KK; ++r) {
    H2U w;
    w.h = l1[r];
    part[(size_t)(c * KK + r) * NQ + qid] = w.u;
  }
}

// ---------------------------------------------------------------------------
// Kernel T: tau[g] = 10th-smallest of the 80 stored f16 upper bounds + eps.
// (>=10 distinct candidates have ub <= tau  =>  tau >= subset md_10 >=
//  global md_10; filter with tau admits every true top-10 member.)
// ---------------------------------------------------------------------------
__global__ __launch_bounds__(256) void tau_kernel(
    const unsigned* __restrict__ part, float* __restrict__ tau_arr) {
  const int g = blockIdx.x * 256 + threadIdx.x;
  float bv[KK];
#pragma unroll
  for (int i = 0; i < KK; ++i) bv[i] = INFINITY;
#pragma unroll
  for (int c = 0; c < CHUNKS; ++c) {
#pragma unroll
    for (int r = 0; r < KK; ++r) {
      H2U w;
      w.u = part[(size_t)(c * KK + r) * NQ + g];
      insf(bv, (float)w.h.x);
      insf(bv, (float)w.h.y);
    }
  }
  tau_arr[g] = bv[KK - 1] + 1e-4f;
}

// ---------------------------------------------------------------------------
// Kernel F: chunked filter with LDS per-thread append (runtime-indexed LDS
// replaces the register cndmask chain). Records global indices with
// md <= tau (true count stored; list capped at FCAP, overflow handled in
// finish). Copy-out stride 29 u32 -> conflict-free.
// ---------------------------------------------------------------------------
__global__ __launch_bounds__(256) void knn_filter(
    const float4* __restrict__ cand4, const float* __restrict__ tau_arr,
    unsigned* __restrict__ fcnt, unsigned short* __restrict__ flist) {
  __shared__ unsigned slds[256 * LSTRIDE];  // 29.7 KB
  const int qg = blockIdx.x >> 2;  // query group 0..15
  const int c = blockIdx.x & 3;    // chunk 0..3
  const int b = blockIdx.y, t = blockIdx.z;
  const float4* __restrict__ src = cand4 + ((size_t)(b * TT + t) * PP);
  const float4* __restrict__ ch = src + c * CSZ;
  const int jbase = c * CSZ;
  const int tid = threadIdx.x;

  const int p = qg * 256 + tid;
  const size_t g = (size_t)(t * BB + b) * PP + p;
  const float4 q = src[p];
  const float tau = tau_arr[g];
  unsigned* my = slds + tid * LSTRIDE;

  int cnt = 0;
  for (int j = 0; j < CSZ; j += 8) {
    float4 c0 = ch[j], c1 = ch[j + 1], c2 = ch[j + 2], c3 = ch[j + 3];
    float4 c4 = ch[j + 4], c5 = ch[j + 5], c6 = ch[j + 6], c7 = ch[j + 7];
    float m0 = md_of(q, c0), m1 = md_of(q, c1), m2 = md_of(q, c2),
          m3 = md_of(q, c3);
    float m4 = md_of(q, c4), m5 = md_of(q, c5), m6 = md_of(q, c6),
          m7 = md_of(q, c7);
#define FLT(mm, jj)                                             \
    if ((mm) <= tau) {                                          \
      if (cnt < FCAP) my[cnt] = (unsigned)(jbase + (jj));       \
      ++cnt;                                                    \
    }
    FLT(m0, j); FLT(m1, j + 1); FLT(m2, j + 2); FLT(m3, j + 3);
    FLT(m4, j + 4); FLT(m5, j + 5); FLT(m6, j + 6); FLT(m7, j + 7);
#undef FLT
  }

  fcnt[(size_t)c * NQ + g] = (unsigned)cnt;  // TRUE count (may exceed FCAP)
#pragma unroll 4
  for (int r = 0; r < FCAP; ++r)
    flist[(size_t)(c * FCAP + r) * NQ + g] = (unsigned short)my[r];
}

// ---------------------------------------------------------------------------
// Kernel G: finish. Fixed-bound UNROLLED survivor loops (round-10 post-mortem:
// runtime-bound loop serialized a scattered-load chain at 1.75 waves/SIMD ->
// 588 us). Predicated insp, clamped addresses for masked lanes; loads issue
// in batches and overlap. Per-chunk inline overflow fallback preserves the
// ascending-j stable insertion order (exactness). Then disp_var.
// ---------------------------------------------------------------------------
__global__ __launch_bounds__(256) void knn_finish(
    const float4* __restrict__ cand4, const float* __restrict__ pts4,
    const float* __restrict__ tau_arr, const unsigned* __restrict__ fcnt,
    const unsigned short* __restrict__ flist, int* __restrict__ idx_out,
    float* __restrict__ dv_out) {
  const int g = blockIdx.x * 256 + threadIdx.x;
  const int t = g >> 14;
  const int rem = g & (BP - 1);
  const int b = rem >> 12;
  const int p = rem & (PP - 1);
  const float4* __restrict__ src = cand4 + ((size_t)(b * TT + t) * PP);
  const float4* __restrict__ src1 =
      (const float4*)pts4 + ((size_t)(b * TT + t + 1) * PP);

  const float4 q = src[p];
  const float tau = tau_arr[g];

  float v[KK];
  int vi[KK];
#pragma unroll
  for (int i = 0; i < KK; ++i) { v[i] = INFINITY; vi[i] = 0; }

#pragma unroll
  for (int c = 0; c < CHUNKS; ++c) {
    const int cn = (int)fcnt[(size_t)c * NQ + g];
    if (cn <= FCAP) {
#pragma unroll
      for (int r = 0; r < FCAP; ++r) {
        int j = (int)flist[(size_t)(c * FCAP + r) * NQ + g];  // coalesced
        const bool valid = r < cn;
        const int js = valid ? j : p;   // safe addr for masked lanes
        float4 cc = src[js];            // independent; issues early
        float mdv = md_of(q, cc);
        if (valid) insp(v, vi, mdv, j);
      }
    } else {
      // overflow fallback (~1e-7/chunk-query; exactness preserved, and kept
      // INLINE so ascending-j insertion order holds across chunks)
      const float4* chb = src + c * CSZ;
      for (int jj = 0; jj < CSZ; ++jj) {
        float mdv = md_of(q, chb[jj]);
        if (mdv <= tau) insp(v, vi, mdv, c * CSZ + jj);
      }
    }
  }

  // disp_var over the 10 selected, in rank order (matches top_k order)
  float4 a1 = src1[p];
  const float dqx = a1.x - q.x, dqy = a1.y - q.y, dqz = a1.z - q.z;
  float s = 0.0f;
  int* myidx = idx_out + (size_t)g * KK;
#pragma unroll
  for (int r = 0; r < KK; ++r) {
    int j = vi[r];
    float4 cc = src[j];
    float4 n1 = src1[j];
    float dx = (n1.x - cc.x) - dqx;
    float dy = (n1.y - cc.y) - dqy;
    float dz = (n1.z - cc.z) - dqz;
    s += fmaf(dx, dx, fmaf(dy, dy, dz * dz));
    myidx[r] = j;
  }
  dv_out[g] = s * (1.0f / KK);
}

// ---------------------------------------------------------------------------
// Kernel B2: transpose encoded[b][d][t*P+p] -> featT[t][b][p][d]  (t < NT)
// ---------------------------------------------------------------------------
__global__ __launch_bounds__(256) void transpose_kernel(
    const float* __restrict__ encoded, float* __restrict__ featT) {
  __shared__ float tile[32][33];
  const int slice = blockIdx.z;  // t*BB + b
  const int t = slice / BB, b = slice % BB;
  const int p0 = blockIdx.x * 32, d0 = blockIdx.y * 32;
  const int tx = threadIdx.x, ty = threadIdx.y;
#pragma unroll
  for (int r = 0; r < 4; ++r) {
    int d = d0 + ty + r * 8;
    tile[ty + r * 8][tx] =
        encoded[((size_t)(b * DD + d)) * (TT * PP) + (size_t)t * PP + p0 + tx];
  }
  __syncthreads();
#pragma unroll
  for (int r = 0; r < 4; ++r) {
    int p = p0 + ty + r * 8;
    featT[((size_t)slice * PP + p) * DD + d0 + tx] = tile[tx][ty + r * 8];
  }
}

// ---------------------------------------------------------------------------
// Kernel N: per-point feature L2 norms (wave per point)
// ---------------------------------------------------------------------------
__global__ __launch_bounds__(256) void norms_kernel(
    const float* __restrict__ featT, float* __restrict__ norms) {
  const int w = threadIdx.x >> 6, lane = threadIdx.x & 63;
  const int wid = blockIdx.x * 4 + w;
  for (int i = 0; i < 32; ++i) {
    const int g = wid * 32 + i;
    float2 f = *(const float2*)(featT + (size_t)g * DD + lane * 2);
    float part = fmaf(f.x, f.x, f.y * f.y);
#pragma unroll
    for (int o = 32; o > 0; o >>= 1) part += __shfl_xor(part, o);
    if (lane == 0) norms[g] = sqrtf(part);
  }
}

// ---------------------------------------------------------------------------
// Kernel C: exact lower-median per t via 4-pass radix select on float bits
// ---------------------------------------------------------------------------
__global__ __launch_bounds__(256) void median_kernel(
    const float* __restrict__ disp_var, float* __restrict__ scale) {
  const int t = blockIdx.x;
  const unsigned* u = (const unsigned*)(disp_var + (size_t)t * BP);
  __shared__ unsigned hist[256];
  __shared__ unsigned sh_prefix;
  __shared__ int sh_rank;
  if (threadIdx.x == 0) { sh_prefix = 0u; sh_rank = (BP - 1) >> 1; }
  __syncthreads();
  for (int pass = 0; pass < 4; ++pass) {
    const int shift = 24 - pass * 8;
    hist[threadIdx.x] = 0u;
    __syncthreads();
    const unsigned hmask = (pass == 0) ? 0u : (0xFFFFFFFFu << (shift + 8));
    const unsigned prefix = sh_prefix;
    for (int i = threadIdx.x; i < BP; i += 256) {
      unsigned v = u[i];
      if ((v & hmask) == prefix) atomicAdd(&hist[(v >> shift) & 255u], 1u);
    }
    __syncthreads();
    if (threadIdx.x == 0) {
      int rank = sh_rank;
      unsigned run = 0u;
      for (int c = 0; c < 256; ++c) {
        unsigned h = hist[c];
        if (run + h > (unsigned)rank) {
          sh_rank = rank - (int)run;
          sh_prefix = prefix | ((unsigned)c << shift);
          break;
        }
        run += h;
      }
    }
    __syncthreads();
  }
  if (threadIdx.x == 0) {
    float med = __uint_as_float(sh_prefix);
    scale[t] = fmaxf(med, 1e-6f);
  }
}

// ---------------------------------------------------------------------------
// Kernel D: cosine similarity + rigidity loss, deterministic block partials
// ---------------------------------------------------------------------------
__global__ __launch_bounds__(256) void cos_loss_kernel(
    const float* __restrict__ featT, const int* __restrict__ idxw,
    const float* __restrict__ norms, const float* __restrict__ dv,
    const float* __restrict__ scale, float* __restrict__ partial) {
  const int w = threadIdx.x >> 6, lane = threadIdx.x & 63;
  __shared__ float wsum[4];
  float acc = 0.0f;
  const int qbase = blockIdx.x * QPB + w * (QPB / 4);
  for (int i = 0; i < QPB / 4; ++i) {
    const int g = qbase + i;
    const int t = g >> 14;
    const int p = g & (PP - 1);
    const int slice = g - p;  // base of this (t,b) slice
    const float* fbase = featT + (size_t)g * DD;
    float2 fq = *(const float2*)(fbase + lane * 2);
    float nq = fmaxf(norms[g], 1e-8f);
    const int* ip = idxw + (size_t)g * KK;
    float msum = 0.0f;
#pragma unroll
    for (int k = 0; k < KK; ++k) {
      int j = ip[k];
      const float* nb = featT + (size_t)(slice + j) * DD;
      float2 fn = *(const float2*)(nb + lane * 2);
      float part = fmaf(fq.x, fn.x, fq.y * fn.y);
#pragma unroll
      for (int o = 32; o > 0; o >>= 1) part += __shfl_xor(part, o);
      float nn = fmaxf(norms[slice + j], 1e-8f);
      msum += part / (nq * nn);
    }
    float mean_sim = msum * (1.0f / KK);
    float rig = expf(-dv[g] / scale[t]);
    acc += rig * (1.0f - mean_sim);
  }
  if (lane == 0) wsum[w] = acc;
  __syncthreads();
  if (threadIdx.x == 0)
    partial[blockIdx.x] = (wsum[0] + wsum[1]) + (wsum[2] + wsum[3]);
}

// ---------------------------------------------------------------------------
// Kernel E: final deterministic reduce -> scalar loss
// ---------------------------------------------------------------------------
__global__ __launch_bounds__(256) void final_reduce_kernel(
    const float* __restrict__ partial, float* __restrict__ out) {
  __shared__ float sh[256];
  float s = 0.0f;
  for (int i = threadIdx.x; i < NBLK_COS; i += 256) s += partial[i];
  sh[threadIdx.x] = s;
  __syncthreads();
  for (int st = 128; st > 0; st >>= 1) {
    if (threadIdx.x < st) sh[threadIdx.x] += sh[threadIdx.x + st];
    __syncthreads();
  }
  if (threadIdx.x == 0) out[0] = sh[0] * (1.0f / (float)NQ);
}

extern "C" void kernel_launch(void* const* d_in, const int* in_sizes, int n_in,
                              void* d_out, int out_size, void* d_ws,
                              size_t ws_size, hipStream_t stream) {
  const float* encoded = (const float*)d_in[0];
  const float* pts4 = (const float*)d_in[1];
  char* ws = (char*)d_ws;
  float* featT = (float*)(ws + OFF_FEATT);
  unsigned* part = (unsigned*)(ws + OFF_PARTV);       // aliases featT
  float4* cand4 = (float4*)(ws + OFF_CAND4);          // aliases featT
  float* tau_arr = (float*)(ws + OFF_TAU);            // aliases featT
  unsigned* fcnt = (unsigned*)(ws + OFF_FCNT);        // aliases featT
  unsigned short* flist = (unsigned short*)(ws + OFF_FLIST);  // aliases featT
  int* idxw = (int*)(ws + OFF_IDX);
  float* dv = (float*)(ws + OFF_DV);
  float* norms = (float*)(ws + OFF_NORM);
  float* scale = (float*)(ws + OFF_SCALE);
  float* partial = (float*)(ws + OFF_PART);
  float* outp = (float*)d_out;

  prep_cand<<<(BB * TT * PP) / 256, 256, 0, stream>>>(pts4, cand4);
  knn_thr_partial<<<dim3(16 * CHUNKS, BB, NT), 256, 0, stream>>>(cand4, part);
  tau_kernel<<<NQ / 256, 256, 0, stream>>>(part, tau_arr);
  knn_filter<<<dim3(16 * CHUNKS, BB, NT), 256, 0, stream>>>(cand4, tau_arr,
                                                            fcnt, flist);
  knn_finish<<<NQ / 256, 256, 0, stream>>>(cand4, pts4, tau_arr, fcnt, flist,
                                           idxw, dv);
  transpose_kernel<<<dim3(PP / 32, DD / 32, NT * BB), dim3(32, 8), 0, stream>>>(
      encoded, featT);
  norms_kernel<<<NBLK_COS, 256, 0, stream>>>(featT, norms);
  median_kernel<<<NT, 256, 0, stream>>>(dv, scale);
  cos_loss_kernel<<<NBLK_COS, 256, 0, stream>>>(featT, idxw, norms, dv, scale,
                                                partial);
  final_reduce_kernel<<<1, 256, 0, stream>>>(partial, outp);
}

// Round 12
// 974.707 us; speedup vs baseline: 1.1482x; 1.1482x over previous
//
#include <hip/hip_runtime.h>
#include <math.h>

// Problem constants (fixed by setup_inputs: B=4, D=128, T=8, P=4096)
#define BB 4
#define DD 128
#define TT 8
#define PP 4096
#define KK 10
#define NT 7              // T-1 frame pairs
#define BP (BB*PP)        // 16384 points per frame across batch
#define NQ (NT*BP)        // 114688 total queries
#define NBLK_COS 896
#define QPB 128           // queries per block in cos kernel (NBLK_COS*QPB == NQ)

#define CHUNKS 4
#define CSZ (PP/CHUNKS)   // 1024 candidates per chunk (filter pass)
#define TSZ 256           // tau-subset slice per block: 4 blocks x 256 = 1024-subset
#define FCAP 28           // per-chunk survivor cap (survivors/chunk ~10+-4; P(>28)~3e-5)
#define LSTRIDE (FCAP+1)  // LDS row stride

// Workspace layout (bytes). Everything below OFF_IDX aliases the featT
// region (58.7 MB) and is fully consumed by knn_merge3 BEFORE
// transpose_kernel writes featT (same-stream ordering).
#define OFF_FEATT 0u                 // NQ*DD floats  = 58,720,256 B
#define OFF_PARTV 0u                 // CHUNKS*KK*NQ uints = 18,350,080 B
#define OFF_CAND4 20971520u          // BB*TT*PP float4 = 2,097,152 B
#define OFF_TAU   23068672u          // NQ floats = 458,752 B
#define OFF_PMD   23527424u          // CHUNKS*KK*NQ f32 = 18,350,080 B
#define OFF_PIX   41877504u          // CHUNKS*KK*NQ u16 =  9,175,040 B (ends 51.05 MB)
#define OFF_IDX   58720256u          // NQ*KK ints    =  4,587,520 B
#define OFF_DV    63307776u          // NQ floats     =    458,752 B
#define OFF_NORM  63766528u          // NQ floats     =    458,752 B
#define OFF_SCALE 64225280u          // NT floats (padded to 256)
#define OFF_PART  64225536u          // NBLK_COS floats

// __builtin_amdgcn_cvt_pkrtz returns __fp16 ext_vector_type(2).
typedef __fp16 f16x2 __attribute__((ext_vector_type(2)));
union H2U { f16x2 h; unsigned u; };

// Packed f16 min/max via inline asm (clang promotes elementwise builtins on
// f16 vectors to f32 — round-8 post-mortem).
__device__ __forceinline__ f16x2 pk_min(f16x2 a, f16x2 b) {
  f16x2 d;
  asm("v_pk_min_f16 %0, %1, %2" : "=v"(d) : "v"(a), "v"(b));
  return d;
}
__device__ __forceinline__ f16x2 pk_max(f16x2 a, f16x2 b) {
  f16x2 d;
  asm("v_pk_max_f16 %0, %1, %2" : "=v"(d) : "v"(a), "v"(b));
  return d;
}

// md = |q-c|^2 computed as (xx_q + xx_c) - 2*inner. MUST be the same
// expression in every kernel (bit-identical md values make the threshold
// argument exact).
__device__ __forceinline__ float md_of(const float4 q, const float4 c) {
  float s = q.w + c.w;
  float inner = fmaf(q.x, c.x, fmaf(q.y, c.y, q.z * c.z));
  return fmaf(-2.0f, inner, s);
}

// Packed-f16 "keep 10 smallest" ladder over two independent candidate
// streams (.x / .y). Values are conservative UPPER bounds of md:
// cvt_pkrtz (toward zero = down for positives) then +2 f16-ulps.
__device__ __forceinline__ void ins2(f16x2 (&bv)[KK], float mdA, float mdB) {
  H2U cv;
  cv.h = __builtin_amdgcn_cvt_pkrtz(mdA, mdB);
  cv.u += 0x00020002u;  // +2 ulps up (values small positive; no NaN/ovf)
  bv[KK - 1] = pk_min(bv[KK - 1], cv.h);
#pragma unroll
  for (int i = KK - 1; i > 0; --i) {
    f16x2 lo = pk_min(bv[i - 1], bv[i]);
    f16x2 hi = pk_max(bv[i - 1], bv[i]);
    bv[i - 1] = lo;
    bv[i] = hi;
  }
}
__device__ __forceinline__ void insh(f16x2 (&bv)[KK], f16x2 h) {
  bv[KK - 1] = pk_min(bv[KK - 1], h);
#pragma unroll
  for (int i = KK - 1; i > 0; --i) {
    f16x2 lo = pk_min(bv[i - 1], bv[i]);
    f16x2 hi = pk_max(bv[i - 1], bv[i]);
    bv[i - 1] = lo;
    bv[i] = hi;
  }
}

// f32 keep-10-smallest (values only), branchless.
__device__ __forceinline__ void insf(float (&bv)[KK], float v) {
  bv[KK - 1] = fminf(bv[KK - 1], v);
#pragma unroll
  for (int i = KK - 1; i > 0; --i) {
    float lo = fminf(bv[i - 1], bv[i]);
    float hi = fmaxf(bv[i - 1], bv[i]);
    bv[i - 1] = lo;
    bv[i] = hi;
  }
}

// Exact stable (md,idx) insert: keep 10 smallest, ascending md; strict-<
// entry/bubble over an ascending-(chunk,md,j) insert stream keeps earlier
// index on ties — exactly jax.lax.top_k's tie rule.
__device__ __forceinline__ void insp(float (&v)[KK], int (&vi)[KK], float md,
                                     int j) {
  bool en = md < v[KK - 1];
  v[KK - 1] = en ? md : v[KK - 1];
  vi[KK - 1] = en ? j : vi[KK - 1];
#pragma unroll
  for (int i = KK - 1; i > 0; --i) {
    bool sw = v[i] < v[i - 1];
    float tv = sw ? v[i - 1] : v[i];
    v[i - 1] = sw ? v[i] : v[i - 1];
    v[i] = tv;
    int ti = sw ? vi[i - 1] : vi[i];
    vi[i - 1] = sw ? vi[i] : vi[i - 1];
    vi[i] = ti;
  }
}

// ---------------------------------------------------------------------------
// Kernel P: precompute (x,y,z,xx) per point.
// ---------------------------------------------------------------------------
__global__ __launch_bounds__(256) void prep_cand(
    const float* __restrict__ pts4, float4* __restrict__ cand4) {
  const int i = blockIdx.x * 256 + threadIdx.x;  // over BB*TT*PP
  float4 v = ((const float4*)pts4)[i];
  v.w = fmaf(v.x, v.x, fmaf(v.y, v.y, v.z * v.z));
  cand4[i] = v;
}

// ---------------------------------------------------------------------------
// Kernel A1: f16 upper bounds of top-10 md over a 1024-candidate SUBSET
// (candidates [0,1024) of the slice; 4 blocks x 256 cands). Validity: the
// 10th-smallest of ANY >=10-element subset upper-bounds the global 10th.
// ---------------------------------------------------------------------------
__global__ __launch_bounds__(256) void knn_thr_partial(
    const float4* __restrict__ cand4, unsigned* __restrict__ part) {
  const int qg = blockIdx.x >> 2;  // query group 0..15
  const int c = blockIdx.x & 3;    // subset slice 0..3
  const int b = blockIdx.y, t = blockIdx.z;
  const float4* __restrict__ src = cand4 + ((size_t)(b * TT + t) * PP);
  const float4* __restrict__ ch = src + c * TSZ;  // subset slice [c*256,..)

  const int p = qg * 256 + threadIdx.x;
  const float4 q = src[p];

  H2U inf2;
  inf2.u = 0x7C007C00u;
  f16x2 l1[KK], l2[KK];
#pragma unroll
  for (int i = 0; i < KK; ++i) { l1[i] = inf2.h; l2[i] = inf2.h; }

  for (int j = 0; j < TSZ; j += 4) {
    float4 c0 = ch[j], c1 = ch[j + 1], c2 = ch[j + 2], c3 = ch[j + 3];
    float md0 = md_of(q, c0);
    float md1 = md_of(q, c1);
    float md2 = md_of(q, c2);
    float md3 = md_of(q, c3);
    ins2(l1, md0, md1);
    ins2(l2, md2, md3);
  }
  // merge stream-pairs: l1 <- per-component union top-10 (streams of 64 >= 10)
#pragma unroll
  for (int r = 0; r < KK; ++r) insh(l1, l2[r]);

  const size_t qid = (size_t)(t * BB + b) * PP + p;
#pragma unroll
  for (int r = 0; r < KK; ++r) {
    H2U w;
    w.h = l1[r];
    part[(size_t)(c * KK + r) * NQ + qid] = w.u;
  }
}

// ---------------------------------------------------------------------------
// Kernel T: tau[g] = 10th-smallest of the 80 stored f16 upper bounds + eps.
// (>=10 distinct candidates have ub <= tau => tau >= subset md_10 >= global
//  md_10; filter with tau admits every true top-10 member.)
// ---------------------------------------------------------------------------
__global__ __launch_bounds__(256) void tau_kernel(
    const unsigned* __restrict__ part, float* __restrict__ tau_arr) {
  const int g = blockIdx.x * 256 + threadIdx.x;
  float bv[KK];
#pragma unroll
  for (int i = 0; i < KK; ++i) bv[i] = INFINITY;
#pragma unroll
  for (int c = 0; c < CHUNKS; ++c) {
#pragma unroll
    for (int r = 0; r < KK; ++r) {
      H2U w;
      w.u = part[(size_t)(c * KK + r) * NQ + g];
      insf(bv, (float)w.h.x);
      insf(bv, (float)w.h.y);
    }
  }
  tau_arr[g] = bv[KK - 1] + 1e-4f;
}

// ---------------------------------------------------------------------------
// Kernel F2: chunked filter that KEEPS md. LDS-append (md,idx) survivors,
// then in-kernel exact per-chunk stable top-10 (insp over <=28 LDS entries —
// no global gathers at all). Rare overflow (cnt>FCAP, P~3e-5) -> direct
// guarded insp rescan of the chunk (exact). Writes per-chunk top-10
// (md f32, idx u16), INF-padded.
// Exactness: every global-top-10 elem has md<=tau (kernel T) => survivor;
// within its chunk <10 elems are smaller and all are survivors => it is in
// the chunk-survivor top-10. Per-chunk list order = (md asc, j asc).
// ---------------------------------------------------------------------------
__global__ __launch_bounds__(256) void knn_filter2(
    const float4* __restrict__ cand4, const float* __restrict__ tau_arr,
    float* __restrict__ ptop_md, unsigned short* __restrict__ ptop_ix) {
  __shared__ float smd[256 * LSTRIDE];           // 29.7 KB
  __shared__ unsigned short six[256 * LSTRIDE];  // 14.8 KB
  const int qg = blockIdx.x >> 2;  // query group 0..15
  const int c = blockIdx.x & 3;    // chunk 0..3
  const int b = blockIdx.y, t = blockIdx.z;
  const float4* __restrict__ src = cand4 + ((size_t)(b * TT + t) * PP);
  const float4* __restrict__ ch = src + c * CSZ;
  const int jbase = c * CSZ;
  const int tid = threadIdx.x;
  const int row = tid * LSTRIDE;

  const int p = qg * 256 + tid;
  const size_t g = (size_t)(t * BB + b) * PP + p;
  const float4 q = src[p];
  const float tau = tau_arr[g];

  int cnt = 0;
  for (int j = 0; j < CSZ; j += 8) {
    float4 c0 = ch[j], c1 = ch[j + 1], c2 = ch[j + 2], c3 = ch[j + 3];
    float4 c4 = ch[j + 4], c5 = ch[j + 5], c6 = ch[j + 6], c7 = ch[j + 7];
    float m0 = md_of(q, c0), m1 = md_of(q, c1), m2 = md_of(q, c2),
          m3 = md_of(q, c3);
    float m4 = md_of(q, c4), m5 = md_of(q, c5), m6 = md_of(q, c6),
          m7 = md_of(q, c7);
#define FLT(mm, jj)                                             \
    if ((mm) <= tau) {                                          \
      if (cnt < FCAP) {                                         \
        smd[row + cnt] = (mm);                                  \
        six[row + cnt] = (unsigned short)(jbase + (jj));        \
      }                                                         \
      ++cnt;                                                    \
    }
    FLT(m0, j); FLT(m1, j + 1); FLT(m2, j + 2); FLT(m3, j + 3);
    FLT(m4, j + 4); FLT(m5, j + 5); FLT(m6, j + 6); FLT(m7, j + 7);
#undef FLT
  }

  // exact per-chunk stable top-10 (ascending-j insert stream)
  float v[KK];
  int vi[KK];
#pragma unroll
  for (int i = 0; i < KK; ++i) { v[i] = INFINITY; vi[i] = 0; }

  if (cnt <= FCAP) {
    for (int r = 0; r < cnt; ++r)
      insp(v, vi, smd[row + r], (int)six[row + r]);
  } else {
    // exact rescan of this chunk (rare)
    for (int jj = 0; jj < CSZ; ++jj) {
      float mdv = md_of(q, ch[jj]);
      if (mdv < v[KK - 1]) insp(v, vi, mdv, jbase + jj);
    }
  }

#pragma unroll
  for (int r = 0; r < KK; ++r) {
    ptop_md[(size_t)(c * KK + r) * NQ + g] = v[r];
    ptop_ix[(size_t)(c * KK + r) * NQ + g] = (unsigned short)vi[r];
  }
}

// ---------------------------------------------------------------------------
// Kernel M3: merge per-chunk top-10 lists (all loads coalesced, fully
// independent) -> exact global stable top-10; then disp_var (the only
// scattered gathers left: 10 fixed (src0,src1) pairs, unrolled).
// ---------------------------------------------------------------------------
__global__ __launch_bounds__(256) void knn_merge3(
    const float4* __restrict__ cand4, const float* __restrict__ pts4,
    const float* __restrict__ ptop_md, const unsigned short* __restrict__ ptop_ix,
    int* __restrict__ idx_out, float* __restrict__ dv_out) {
  const int g = blockIdx.x * 256 + threadIdx.x;
  const int t = g >> 14;
  const int rem = g & (BP - 1);
  const int b = rem >> 12;
  const int p = rem & (PP - 1);
  const float4* __restrict__ src = cand4 + ((size_t)(b * TT + t) * PP);
  const float4* __restrict__ src1 =
      (const float4*)pts4 + ((size_t)(b * TT + t + 1) * PP);

  float v[KK];
  int vi[KK];
#pragma unroll
  for (int i = 0; i < KK; ++i) { v[i] = INFINITY; vi[i] = 0; }

#pragma unroll
  for (int c = 0; c < CHUNKS; ++c) {
    float md_in[KK];
    int ix_in[KK];
#pragma unroll
    for (int r = 0; r < KK; ++r) {
      md_in[r] = ptop_md[(size_t)(c * KK + r) * NQ + g];
      ix_in[r] = (int)ptop_ix[(size_t)(c * KK + r) * NQ + g];
    }
#pragma unroll
    for (int r = 0; r < KK; ++r) insp(v, vi, md_in[r], ix_in[r]);
  }

  // disp_var over the 10 selected, in rank order (matches top_k order)
  const float4 q = src[p];
  float4 a1 = src1[p];
  const float dqx = a1.x - q.x, dqy = a1.y - q.y, dqz = a1.z - q.z;
  float s = 0.0f;
  int* myidx = idx_out + (size_t)g * KK;
#pragma unroll
  for (int r = 0; r < KK; ++r) {
    int j = vi[r];
    float4 cc = src[j];
    float4 n1 = src1[j];
    float dx = (n1.x - cc.x) - dqx;
    float dy = (n1.y - cc.y) - dqy;
    float dz = (n1.z - cc.z) - dqz;
    s += fmaf(dx, dx, fmaf(dy, dy, dz * dz));
    myidx[r] = j;
  }
  dv_out[g] = s * (1.0f / KK);
}

// ---------------------------------------------------------------------------
// Kernel B2: transpose encoded[b][d][t*P+p] -> featT[t][b][p][d]  (t < NT)
// ---------------------------------------------------------------------------
__global__ __launch_bounds__(256) void transpose_kernel(
    const float* __restrict__ encoded, float* __restrict__ featT) {
  __shared__ float tile[32][33];
  const int slice = blockIdx.z;  // t*BB + b
  const int t = slice / BB, b = slice % BB;
  const int p0 = blockIdx.x * 32, d0 = blockIdx.y * 32;
  const int tx = threadIdx.x, ty = threadIdx.y;
#pragma unroll
  for (int r = 0; r < 4; ++r) {
    int d = d0 + ty + r * 8;
    tile[ty + r * 8][tx] =
        encoded[((size_t)(b * DD + d)) * (TT * PP) + (size_t)t * PP + p0 + tx];
  }
  __syncthreads();
#pragma unroll
  for (int r = 0; r < 4; ++r) {
    int p = p0 + ty + r * 8;
    featT[((size_t)slice * PP + p) * DD + d0 + tx] = tile[tx][ty + r * 8];
  }
}

// ---------------------------------------------------------------------------
// Kernel N: per-point feature L2 norms (wave per point)
// ---------------------------------------------------------------------------
__global__ __launch_bounds__(256) void norms_kernel(
    const float* __restrict__ featT, float* __restrict__ norms) {
  const int w = threadIdx.x >> 6, lane = threadIdx.x & 63;
  const int wid = blockIdx.x * 4 + w;
  for (int i = 0; i < 32; ++i) {
    const int g = wid * 32 + i;
    float2 f = *(const float2*)(featT + (size_t)g * DD + lane * 2);
    float part = fmaf(f.x, f.x, f.y * f.y);
#pragma unroll
    for (int o = 32; o > 0; o >>= 1) part += __shfl_xor(part, o);
    if (lane == 0) norms[g] = sqrtf(part);
  }
}

// ---------------------------------------------------------------------------
// Kernel C: exact lower-median per t via 4-pass radix select on float bits
// ---------------------------------------------------------------------------
__global__ __launch_bounds__(256) void median_kernel(
    const float* __restrict__ disp_var, float* __restrict__ scale) {
  const int t = blockIdx.x;
  const unsigned* u = (const unsigned*)(disp_var + (size_t)t * BP);
  __shared__ unsigned hist[256];
  __shared__ unsigned sh_prefix;
  __shared__ int sh_rank;
  if (threadIdx.x == 0) { sh_prefix = 0u; sh_rank = (BP - 1) >> 1; }
  __syncthreads();
  for (int pass = 0; pass < 4; ++pass) {
    const int shift = 24 - pass * 8;
    hist[threadIdx.x] = 0u;
    __syncthreads();
    const unsigned hmask = (pass == 0) ? 0u : (0xFFFFFFFFu << (shift + 8));
    const unsigned prefix = sh_prefix;
    for (int i = threadIdx.x; i < BP; i += 256) {
      unsigned v = u[i];
      if ((v & hmask) == prefix) atomicAdd(&hist[(v >> shift) & 255u], 1u);
    }
    __syncthreads();
    if (threadIdx.x == 0) {
      int rank = sh_rank;
      unsigned run = 0u;
      for (int c = 0; c < 256; ++c) {
        unsigned h = hist[c];
        if (run + h > (unsigned)rank) {
          sh_rank = rank - (int)run;
          sh_prefix = prefix | ((unsigned)c << shift);
          break;
        }
        run += h;
      }
    }
    __syncthreads();
  }
  if (threadIdx.x == 0) {
    float med = __uint_as_float(sh_prefix);
    scale[t] = fmaxf(med, 1e-6f);
  }
}

// ---------------------------------------------------------------------------
// Kernel D: cosine similarity + rigidity loss, deterministic block partials
// ---------------------------------------------------------------------------
__global__ __launch_bounds__(256) void cos_loss_kernel(
    const float* __restrict__ featT, const int* __restrict__ idxw,
    const float* __restrict__ norms, const float* __restrict__ dv,
    const float* __restrict__ scale, float* __restrict__ partial) {
  const int w = threadIdx.x >> 6, lane = threadIdx.x & 63;
  __shared__ float wsum[4];
  float acc = 0.0f;
  const int qbase = blockIdx.x * QPB + w * (QPB / 4);
  for (int i = 0; i < QPB / 4; ++i) {
    const int g = qbase + i;
    const int t = g >> 14;
    const int p = g & (PP - 1);
    const int slice = g - p;  // base of this (t,b) slice
    const float* fbase = featT + (size_t)g * DD;
    float2 fq = *(const float2*)(fbase + lane * 2);
    float nq = fmaxf(norms[g], 1e-8f);
    const int* ip = idxw + (size_t)g * KK;
    float msum = 0.0f;
#pragma unroll
    for (int k = 0; k < KK; ++k) {
      int j = ip[k];
      const float* nb = featT + (size_t)(slice + j) * DD;
      float2 fn = *(const float2*)(nb + lane * 2);
      float part = fmaf(fq.x, fn.x, fq.y * fn.y);
#pragma unroll
      for (int o = 32; o > 0; o >>= 1) part += __shfl_xor(part, o);
      float nn = fmaxf(norms[slice + j], 1e-8f);
      msum += part / (nq * nn);
    }
    float mean_sim = msum * (1.0f / KK);
    float rig = expf(-dv[g] / scale[t]);
    acc += rig * (1.0f - mean_sim);
  }
  if (lane == 0) wsum[w] = acc;
  __syncthreads();
  if (threadIdx.x == 0)
    partial[blockIdx.x] = (wsum[0] + wsum[1]) + (wsum[2] + wsum[3]);
}

// ---------------------------------------------------------------------------
// Kernel E: final deterministic reduce -> scalar loss
// ---------------------------------------------------------------------------
__global__ __launch_bounds__(256) void final_reduce_kernel(
    const float* __restrict__ partial, float* __restrict__ out) {
  __shared__ float sh[256];
  float s = 0.0f;
  for (int i = threadIdx.x; i < NBLK_COS; i += 256) s += partial[i];
  sh[threadIdx.x] = s;
  __syncthreads();
  for (int st = 128; st > 0; st >>= 1) {
    if (threadIdx.x < st) sh[threadIdx.x] += sh[threadIdx.x + st];
    __syncthreads();
  }
  if (threadIdx.x == 0) out[0] = sh[0] * (1.0f / (float)NQ);
}

extern "C" void kernel_launch(void* const* d_in, const int* in_sizes, int n_in,
                              void* d_out, int out_size, void* d_ws,
                              size_t ws_size, hipStream_t stream) {
  const float* encoded = (const float*)d_in[0];
  const float* pts4 = (const float*)d_in[1];
  char* ws = (char*)d_ws;
  float* featT = (float*)(ws + OFF_FEATT);
  unsigned* part = (unsigned*)(ws + OFF_PARTV);       // aliases featT
  float4* cand4 = (float4*)(ws + OFF_CAND4);          // aliases featT
  float* tau_arr = (float*)(ws + OFF_TAU);            // aliases featT
  float* ptop_md = (float*)(ws + OFF_PMD);            // aliases featT
  unsigned short* ptop_ix = (unsigned short*)(ws + OFF_PIX);  // aliases featT
  int* idxw = (int*)(ws + OFF_IDX);
  float* dv = (float*)(ws + OFF_DV);
  float* norms = (float*)(ws + OFF_NORM);
  float* scale = (float*)(ws + OFF_SCALE);
  float* partial = (float*)(ws + OFF_PART);
  float* outp = (float*)d_out;

  prep_cand<<<(BB * TT * PP) / 256, 256, 0, stream>>>(pts4, cand4);
  knn_thr_partial<<<dim3(16 * CHUNKS, BB, NT), 256, 0, stream>>>(cand4, part);
  tau_kernel<<<NQ / 256, 256, 0, stream>>>(part, tau_arr);
  knn_filter2<<<dim3(16 * CHUNKS, BB, NT), 256, 0, stream>>>(cand4, tau_arr,
                                                             ptop_md, ptop_ix);
  knn_merge3<<<NQ / 256, 256, 0, stream>>>(cand4, pts4, ptop_md, ptop_ix,
                                           idxw, dv);
  transpose_kernel<<<dim3(PP / 32, DD / 32, NT * BB), dim3(32, 8), 0, stream>>>(
      encoded, featT);
  norms_kernel<<<NBLK_COS, 256, 0, stream>>>(featT, norms);
  median_kernel<<<NT, 256, 0, stream>>>(dv, scale);
  cos_loss_kernel<<<NBLK_COS, 256, 0, stream>>>(featT, idxw, norms, dv, scale,
                                                partial);
  final_reduce_kernel<<<1, 256, 0, stream>>>(partial, outp);
}

// Round 13
// 843.097 us; speedup vs baseline: 1.3275x; 1.1561x over previous
//
#include <hip/hip_runtime.h>
#include <math.h>

// Problem constants (fixed by setup_inputs: B=4, D=128, T=8, P=4096)
#define BB 4
#define DD 128
#define TT 8
#define PP 4096
#define KK 10
#define NT 7              // T-1 frame pairs
#define BP (BB*PP)        // 16384 points per frame across batch
#define NQ (NT*BP)        // 114688 total queries
#define NBLK_COS 896
#define QPB 128           // queries per block in cos kernel (NBLK_COS*QPB == NQ)

#define CHUNKS 4
#define CSZ (PP/CHUNKS)   // 1024 candidates per chunk
#define SCAP 12           // keys kept per chunk (10 + 2 slack for f16 ties)

// Workspace layout (bytes). keys + cand4 alias the featT region (58.7 MB)
// and are fully consumed by knn_select BEFORE transpose_kernel writes featT
// (same-stream ordering).
#define OFF_FEATT 0u                 // NQ*DD floats  = 58,720,256 B
#define OFF_KEYS  0u                 // CHUNKS*SCAP*NQ u32 = 22,020,096 B
#define OFF_CAND4 22020096u          // BB*TT*PP float4 = 2,097,152 B (ends 24.1 MB)
#define OFF_IDX   58720256u          // NQ*KK ints    =  4,587,520 B
#define OFF_DV    63307776u          // NQ floats     =    458,752 B
#define OFF_NORM  63766528u          // NQ floats     =    458,752 B
#define OFF_SCALE 64225280u          // NT floats (padded to 256)
#define OFF_PART  64225536u          // NBLK_COS floats

// __builtin_amdgcn_cvt_pkrtz returns __fp16 ext_vector_type(2).
typedef __fp16 f16x2 __attribute__((ext_vector_type(2)));
union H2U { f16x2 h; unsigned u; };

// md = |q-c|^2 computed as (xx_q + xx_c) - 2*inner. Identical expression in
// every kernel (bit-identical md values). Self-distance is exactly 0.
__device__ __forceinline__ float md_of(const float4 q, const float4 c) {
  float s = q.w + c.w;
  float inner = fmaf(q.x, c.x, fmaf(q.y, c.y, q.z * c.z));
  return fmaf(-2.0f, inner, s);
}

// Sortable u32 key: (f16 upper bound of md) << 16 | j.
// cvt_pkrtz rounds toward zero (= down for md >= 0); +2 f16-ulps makes the
// high half a conservative upper bound, monotone in md. For non-negative
// f16, bit pattern order == value order, so u32 order == (md-bound asc,
// j asc) — exactly jax.lax.top_k's tie rule.
__device__ __forceinline__ unsigned key_of(float md, int j) {
  H2U u;
  u.h = __builtin_amdgcn_cvt_pkrtz(md, md);  // both halves = f16(md)
  return (u.u & 0xFFFF0000u) + (0x20000u + (unsigned)j);  // +2ulp<<16 | j
}

// Branchless keep-SCAP-smallest u32 ladder: 23 VALU (v_min/v_max_u32).
__device__ __forceinline__ void insu(unsigned (&bk)[SCAP], unsigned k) {
  bk[SCAP - 1] = bk[SCAP - 1] < k ? bk[SCAP - 1] : k;
#pragma unroll
  for (int i = SCAP - 1; i > 0; --i) {
    unsigned a = bk[i - 1], b = bk[i];
    unsigned lo = a < b ? a : b;
    unsigned hi = a < b ? b : a;
    bk[i - 1] = lo;
    bk[i] = hi;
  }
}

// Exact stable lexicographic (md, idx) keep-10-smallest insert. Fully
// order-independent (ties broken by smaller idx), so insertion order of the
// 48 survivors does not matter. Matches jax.lax.top_k set AND order.
__device__ __forceinline__ void insl(float (&v)[KK], int (&vi)[KK], float md,
                                     int j) {
  bool en = (md < v[KK - 1]) || (md == v[KK - 1] && j < vi[KK - 1]);
  v[KK - 1] = en ? md : v[KK - 1];
  vi[KK - 1] = en ? j : vi[KK - 1];
#pragma unroll
  for (int i = KK - 1; i > 0; --i) {
    bool sw = (v[i] < v[i - 1]) || (v[i] == v[i - 1] && vi[i] < vi[i - 1]);
    float tv = sw ? v[i - 1] : v[i];
    v[i - 1] = sw ? v[i] : v[i - 1];
    v[i] = tv;
    int ti = sw ? vi[i - 1] : vi[i];
    vi[i - 1] = sw ? vi[i] : vi[i - 1];
    vi[i] = ti;
  }
}

// ---------------------------------------------------------------------------
// Kernel P: precompute (x,y,z,xx) per point.
// ---------------------------------------------------------------------------
__global__ __launch_bounds__(256) void prep_cand(
    const float* __restrict__ pts4, float4* __restrict__ cand4) {
  const int i = blockIdx.x * 256 + threadIdx.x;  // over BB*TT*PP
  float4 v = ((const float4*)pts4)[i];
  v.w = fmaf(v.x, v.x, fmaf(v.y, v.y, v.z * v.z));
  cand4[i] = v;
}

// ---------------------------------------------------------------------------
// Kernel S: one-pass chunked KNN scan. Each block scans ONE 1024-candidate
// chunk for 256 queries (thread per query); candidate reads are wave-uniform
// -> scalar loads; the u32 ladder keeps the 12 smallest (md-ub, j) keys.
// No LDS, no branches in the hot loop. Containment: the true top-10 members
// of a chunk are among its 12 smallest keys (10 + 2 slack; f16 bound is
// monotone in md, continuous input data).
// ---------------------------------------------------------------------------
__global__ __launch_bounds__(256) void knn_scan(
    const float4* __restrict__ cand4, unsigned* __restrict__ keys) {
  const int qg = blockIdx.x >> 2;  // query group 0..15
  const int c = blockIdx.x & 3;    // chunk 0..3
  const int b = blockIdx.y, t = blockIdx.z;
  const float4* __restrict__ src = cand4 + ((size_t)(b * TT + t) * PP);
  const float4* __restrict__ ch = src + c * CSZ;
  const int jbase = c * CSZ;

  const int p = qg * 256 + threadIdx.x;
  const float4 q = src[p];

  unsigned bk[SCAP];
#pragma unroll
  for (int i = 0; i < SCAP; ++i) bk[i] = 0xFFFFFFFFu;

  for (int j = 0; j < CSZ; j += 4) {
    float4 c0 = ch[j], c1 = ch[j + 1], c2 = ch[j + 2], c3 = ch[j + 3];
    float m0 = md_of(q, c0);
    float m1 = md_of(q, c1);
    float m2 = md_of(q, c2);
    float m3 = md_of(q, c3);
    insu(bk, key_of(m0, jbase + j));
    insu(bk, key_of(m1, jbase + j + 1));
    insu(bk, key_of(m2, jbase + j + 2));
    insu(bk, key_of(m3, jbase + j + 3));
  }

  const size_t g = (size_t)(t * BB + b) * PP + p;
#pragma unroll
  for (int r = 0; r < SCAP; ++r)
    keys[(size_t)(c * SCAP + r) * NQ + g] = bk[r];
}

// ---------------------------------------------------------------------------
// Kernel G: select. Per query: 48 coalesced key loads (all valid — each
// chunk has 1024 >= 12 real candidates, so no padding ever survives), 48
// independent unrolled cand4 gathers (L2-hot 64 KB slice), exact f32 md
// recompute, order-independent lexicographic stable top-10, disp_var.
// No runtime loop bounds, no divergent fallbacks (r10-r12 post-mortems).
// ---------------------------------------------------------------------------
__global__ __launch_bounds__(256) void knn_select(
    const float4* __restrict__ cand4, const float* __restrict__ pts4,
    const unsigned* __restrict__ keys, int* __restrict__ idx_out,
    float* __restrict__ dv_out) {
  const int g = blockIdx.x * 256 + threadIdx.x;
  const int t = g >> 14;
  const int rem = g & (BP - 1);
  const int b = rem >> 12;
  const int p = rem & (PP - 1);
  const float4* __restrict__ src = cand4 + ((size_t)(b * TT + t) * PP);
  const float4* __restrict__ src1 =
      (const float4*)pts4 + ((size_t)(b * TT + t + 1) * PP);

  const float4 q = src[p];

  float v[KK];
  int vi[KK];
#pragma unroll
  for (int i = 0; i < KK; ++i) { v[i] = INFINITY; vi[i] = 0x7FFFFFFF; }

#pragma unroll
  for (int c = 0; c < CHUNKS; ++c) {
#pragma unroll
    for (int r = 0; r < SCAP; ++r) {
      unsigned k = keys[(size_t)(c * SCAP + r) * NQ + g];
      int j = (int)(k & 0xFFFFu);
      float mdv = md_of(q, src[j]);
      insl(v, vi, mdv, j);
    }
  }

  // disp_var over the 10 selected, in rank order (matches top_k order)
  float4 a1 = src1[p];
  const float dqx = a1.x - q.x, dqy = a1.y - q.y, dqz = a1.z - q.z;
  float s = 0.0f;
  int* myidx = idx_out + (size_t)g * KK;
#pragma unroll
  for (int r = 0; r < KK; ++r) {
    int j = vi[r];
    float4 cc = src[j];
    float4 n1 = src1[j];
    float dx = (n1.x - cc.x) - dqx;
    float dy = (n1.y - cc.y) - dqy;
    float dz = (n1.z - cc.z) - dqz;
    s += fmaf(dx, dx, fmaf(dy, dy, dz * dz));
    myidx[r] = j;
  }
  dv_out[g] = s * (1.0f / KK);
}

// ---------------------------------------------------------------------------
// Kernel B2: transpose encoded[b][d][t*P+p] -> featT[t][b][p][d]  (t < NT)
// ---------------------------------------------------------------------------
__global__ __launch_bounds__(256) void transpose_kernel(
    const float* __restrict__ encoded, float* __restrict__ featT) {
  __shared__ float tile[32][33];
  const int slice = blockIdx.z;  // t*BB + b
  const int t = slice / BB, b = slice % BB;
  const int p0 = blockIdx.x * 32, d0 = blockIdx.y * 32;
  const int tx = threadIdx.x, ty = threadIdx.y;
#pragma unroll
  for (int r = 0; r < 4; ++r) {
    int d = d0 + ty + r * 8;
    tile[ty + r * 8][tx] =
        encoded[((size_t)(b * DD + d)) * (TT * PP) + (size_t)t * PP + p0 + tx];
  }
  __syncthreads();
#pragma unroll
  for (int r = 0; r < 4; ++r) {
    int p = p0 + ty + r * 8;
    featT[((size_t)slice * PP + p) * DD + d0 + tx] = tile[tx][ty + r * 8];
  }
}

// ---------------------------------------------------------------------------
// Kernel N: per-point feature L2 norms (wave per point)
// ---------------------------------------------------------------------------
__global__ __launch_bounds__(256) void norms_kernel(
    const float* __restrict__ featT, float* __restrict__ norms) {
  const int w = threadIdx.x >> 6, lane = threadIdx.x & 63;
  const int wid = blockIdx.x * 4 + w;
  for (int i = 0; i < 32; ++i) {
    const int g = wid * 32 + i;
    float2 f = *(const float2*)(featT + (size_t)g * DD + lane * 2);
    float part = fmaf(f.x, f.x, f.y * f.y);
#pragma unroll
    for (int o = 32; o > 0; o >>= 1) part += __shfl_xor(part, o);
    if (lane == 0) norms[g] = sqrtf(part);
  }
}

// ---------------------------------------------------------------------------
// Kernel C: exact lower-median per t via 4-pass radix select on float bits
// ---------------------------------------------------------------------------
__global__ __launch_bounds__(256) void median_kernel(
    const float* __restrict__ disp_var, float* __restrict__ scale) {
  const int t = blockIdx.x;
  const unsigned* u = (const unsigned*)(disp_var + (size_t)t * BP);
  __shared__ unsigned hist[256];
  __shared__ unsigned sh_prefix;
  __shared__ int sh_rank;
  if (threadIdx.x == 0) { sh_prefix = 0u; sh_rank = (BP - 1) >> 1; }
  __syncthreads();
  for (int pass = 0; pass < 4; ++pass) {
    const int shift = 24 - pass * 8;
    hist[threadIdx.x] = 0u;
    __syncthreads();
    const unsigned hmask = (pass == 0) ? 0u : (0xFFFFFFFFu << (shift + 8));
    const unsigned prefix = sh_prefix;
    for (int i = threadIdx.x; i < BP; i += 256) {
      unsigned v = u[i];
      if ((v & hmask) == prefix) atomicAdd(&hist[(v >> shift) & 255u], 1u);
    }
    __syncthreads();
    if (threadIdx.x == 0) {
      int rank = sh_rank;
      unsigned run = 0u;
      for (int c = 0; c < 256; ++c) {
        unsigned h = hist[c];
        if (run + h > (unsigned)rank) {
          sh_rank = rank - (int)run;
          sh_prefix = prefix | ((unsigned)c << shift);
          break;
        }
        run += h;
      }
    }
    __syncthreads();
  }
  if (threadIdx.x == 0) {
    float med = __uint_as_float(sh_prefix);
    scale[t] = fmaxf(med, 1e-6f);
  }
}

// ---------------------------------------------------------------------------
// Kernel D: cosine similarity + rigidity loss, deterministic block partials
// ---------------------------------------------------------------------------
__global__ __launch_bounds__(256) void cos_loss_kernel(
    const float* __restrict__ featT, const int* __restrict__ idxw,
    const float* __restrict__ norms, const float* __restrict__ dv,
    const float* __restrict__ scale, float* __restrict__ partial) {
  const int w = threadIdx.x >> 6, lane = threadIdx.x & 63;
  __shared__ float wsum[4];
  float acc = 0.0f;
  const int qbase = blockIdx.x * QPB + w * (QPB / 4);
  for (int i = 0; i < QPB / 4; ++i) {
    const int g = qbase + i;
    const int t = g >> 14;
    const int p = g & (PP - 1);
    const int slice = g - p;  // base of this (t,b) slice
    const float* fbase = featT + (size_t)g * DD;
    float2 fq = *(const float2*)(fbase + lane * 2);
    float nq = fmaxf(norms[g], 1e-8f);
    const int* ip = idxw + (size_t)g * KK;
    float msum = 0.0f;
#pragma unroll
    for (int k = 0; k < KK; ++k) {
      int j = ip[k];
      const float* nb = featT + (size_t)(slice + j) * DD;
      float2 fn = *(const float2*)(nb + lane * 2);
      float part = fmaf(fq.x, fn.x, fq.y * fn.y);
#pragma unroll
      for (int o = 32; o > 0; o >>= 1) part += __shfl_xor(part, o);
      float nn = fmaxf(norms[slice + j], 1e-8f);
      msum += part / (nq * nn);
    }
    float mean_sim = msum * (1.0f / KK);
    float rig = expf(-dv[g] / scale[t]);
    acc += rig * (1.0f - mean_sim);
  }
  if (lane == 0) wsum[w] = acc;
  __syncthreads();
  if (threadIdx.x == 0)
    partial[blockIdx.x] = (wsum[0] + wsum[1]) + (wsum[2] + wsum[3]);
}

// ---------------------------------------------------------------------------
// Kernel E: final deterministic reduce -> scalar loss
// ---------------------------------------------------------------------------
__global__ __launch_bounds__(256) void final_reduce_kernel(
    const float* __restrict__ partial, float* __restrict__ out) {
  __shared__ float sh[256];
  float s = 0.0f;
  for (int i = threadIdx.x; i < NBLK_COS; i += 256) s += partial[i];
  sh[threadIdx.x] = s;
  __syncthreads();
  for (int st = 128; st > 0; st >>= 1) {
    if (threadIdx.x < st) sh[threadIdx.x] += sh[threadIdx.x + st];
    __syncthreads();
  }
  if (threadIdx.x == 0) out[0] = sh[0] * (1.0f / (float)NQ);
}

extern "C" void kernel_launch(void* const* d_in, const int* in_sizes, int n_in,
                              void* d_out, int out_size, void* d_ws,
                              size_t ws_size, hipStream_t stream) {
  const float* encoded = (const float*)d_in[0];
  const float* pts4 = (const float*)d_in[1];
  char* ws = (char*)d_ws;
  float* featT = (float*)(ws + OFF_FEATT);
  unsigned* keys = (unsigned*)(ws + OFF_KEYS);   // aliases featT (consumed 1st)
  float4* cand4 = (float4*)(ws + OFF_CAND4);     // aliases featT (consumed 1st)
  int* idxw = (int*)(ws + OFF_IDX);
  float* dv = (float*)(ws + OFF_DV);
  float* norms = (float*)(ws + OFF_NORM);
  float* scale = (float*)(ws + OFF_SCALE);
  float* partial = (float*)(ws + OFF_PART);
  float* outp = (float*)d_out;

  prep_cand<<<(BB * TT * PP) / 256, 256, 0, stream>>>(pts4, cand4);
  knn_scan<<<dim3(16 * CHUNKS, BB, NT), 256, 0, stream>>>(cand4, keys);
  knn_select<<<NQ / 256, 256, 0, stream>>>(cand4, pts4, keys, idxw, dv);
  transpose_kernel<<<dim3(PP / 32, DD / 32, NT * BB), dim3(32, 8), 0, stream>>>(
      encoded, featT);
  norms_kernel<<<NBLK_COS, 256, 0, stream>>>(featT, norms);
  median_kernel<<<NT, 256, 0, stream>>>(dv, scale);
  cos_loss_kernel<<<NBLK_COS, 256, 0, stream>>>(featT, idxw, norms, dv, scale,
                                                partial);
  final_reduce_kernel<<<1, 256, 0, stream>>>(partial, outp);
}

// Round 14
// 839.293 us; speedup vs baseline: 1.3335x; 1.0045x over previous
//
#include <hip/hip_runtime.h>
#include <math.h>

// Problem constants (fixed by setup_inputs: B=4, D=128, T=8, P=4096)
#define BB 4
#define DD 128
#define TT 8
#define PP 4096
#define KK 10
#define NT 7              // T-1 frame pairs
#define BP (BB*PP)        // 16384 points per frame across batch
#define NQ (NT*BP)        // 114688 total queries
#define NBLK_COS 896
#define QPB 128           // queries per block in cos kernel (NBLK_COS*QPB == NQ)

#define CHUNKS 4
#define CSZ (PP/CHUNKS)   // 1024 candidates per chunk
#define SCAP 12           // keys kept per chunk (10 + 2 slack for bucket ties)

// Workspace layout (bytes). keys + cand4 alias the featT region (58.7 MB)
// and are fully consumed by knn_select BEFORE transpose_kernel writes featT
// (same-stream ordering).
#define OFF_FEATT 0u                 // NQ*DD floats  = 58,720,256 B
#define OFF_KEYS  0u                 // CHUNKS*SCAP*NQ u32 = 22,020,096 B
#define OFF_CAND4 22020096u          // BB*TT*PP float4 = 2,097,152 B (ends 24.1 MB)
#define OFF_IDX   58720256u          // NQ*KK ints    =  4,587,520 B
#define OFF_DV    63307776u          // NQ floats     =    458,752 B
#define OFF_NORM  63766528u          // NQ floats     =    458,752 B
#define OFF_SCALE 64225280u          // NT floats (padded to 256)
#define OFF_PART  64225536u          // NBLK_COS floats

// u32 min/max via inline asm: clang expands the ternary pattern into
// v_cmp + 2x v_cndmask (3 ops/exchange, round-13 post-mortem: 66 VALU/cand
// measured vs 31 intended). v_min_u32/v_max_u32 are 1 op each.
__device__ __forceinline__ unsigned umin_(unsigned a, unsigned b) {
  unsigned d;
  asm("v_min_u32 %0, %1, %2" : "=v"(d) : "v"(a), "v"(b));
  return d;
}
__device__ __forceinline__ unsigned umax_(unsigned a, unsigned b) {
  unsigned d;
  asm("v_max_u32 %0, %1, %2" : "=v"(d) : "v"(a), "v"(b));
  return d;
}

// md = |q-c|^2 computed as (xx_q + xx_c) - 2*inner. Identical expression in
// every kernel (bit-identical md values). Self-distance is exactly 0.
__device__ __forceinline__ float md_of(const float4 q, const float4 c) {
  float s = q.w + c.w;
  float inner = fmaf(q.x, c.x, fmaf(q.y, c.y, q.z * c.z));
  return fmaf(-2.0f, inner, s);
}

// Sortable u32 key: (f32 bits of md, low 12 bits truncated) | j.
// For non-negative floats, bit order == value order and truncation is
// monotone non-decreasing, so u32 key order == (md-bucket asc, j asc) —
// jax.lax.top_k's tie rule within ~2^-12 relative buckets. fmaxf clamps
// hypothetical tiny-negative rounding results (sign bit would break
// monotonicity). Select recomputes exact f32 md, so only CONTAINMENT of
// the true top-10 in the kept 4x12 is needed (2-slot slack per chunk).
__device__ __forceinline__ unsigned key_of(float md, int j) {
  unsigned b = __float_as_uint(fmaxf(md, 0.0f));
  return (b & 0xFFFFF000u) | (unsigned)j;  // j < 4096 fits 12 bits
}

// Branchless keep-SCAP-smallest u32 ladder: 23 VALU via v_min/v_max_u32.
__device__ __forceinline__ void insu(unsigned (&bk)[SCAP], unsigned k) {
  bk[SCAP - 1] = umin_(bk[SCAP - 1], k);
#pragma unroll
  for (int i = SCAP - 1; i > 0; --i) {
    unsigned lo = umin_(bk[i - 1], bk[i]);
    unsigned hi = umax_(bk[i - 1], bk[i]);
    bk[i - 1] = lo;
    bk[i] = hi;
  }
}

// Exact stable lexicographic (md, idx) keep-10-smallest insert. Fully
// order-independent (ties broken by smaller idx), so insertion order of the
// 48 survivors does not matter. Matches jax.lax.top_k set AND order.
__device__ __forceinline__ void insl(float (&v)[KK], int (&vi)[KK], float md,
                                     int j) {
  bool en = (md < v[KK - 1]) || (md == v[KK - 1] && j < vi[KK - 1]);
  v[KK - 1] = en ? md : v[KK - 1];
  vi[KK - 1] = en ? j : vi[KK - 1];
#pragma unroll
  for (int i = KK - 1; i > 0; --i) {
    bool sw = (v[i] < v[i - 1]) || (v[i] == v[i - 1] && vi[i] < vi[i - 1]);
    float tv = sw ? v[i - 1] : v[i];
    v[i - 1] = sw ? v[i] : v[i - 1];
    v[i] = tv;
    int ti = sw ? vi[i - 1] : vi[i];
    vi[i - 1] = sw ? vi[i] : vi[i - 1];
    vi[i] = ti;
  }
}

// ---------------------------------------------------------------------------
// Kernel P: precompute (x,y,z,xx) per point.
// ---------------------------------------------------------------------------
__global__ __launch_bounds__(256) void prep_cand(
    const float* __restrict__ pts4, float4* __restrict__ cand4) {
  const int i = blockIdx.x * 256 + threadIdx.x;  // over BB*TT*PP
  float4 v = ((const float4*)pts4)[i];
  v.w = fmaf(v.x, v.x, fmaf(v.y, v.y, v.z * v.z));
  cand4[i] = v;
}

// ---------------------------------------------------------------------------
// Kernel S: one-pass chunked KNN scan. Each block scans ONE 1024-candidate
// chunk for 256 queries (thread per query); candidate reads are wave-uniform
// -> scalar loads; the u32 ladder keeps the 12 smallest (md-bucket, j) keys.
// No LDS, no branches in the hot loop.
// ---------------------------------------------------------------------------
__global__ __launch_bounds__(256) void knn_scan(
    const float4* __restrict__ cand4, unsigned* __restrict__ keys) {
  const int qg = blockIdx.x >> 2;  // query group 0..15
  const int c = blockIdx.x & 3;    // chunk 0..3
  const int b = blockIdx.y, t = blockIdx.z;
  const float4* __restrict__ src = cand4 + ((size_t)(b * TT + t) * PP);
  const float4* __restrict__ ch = src + c * CSZ;
  const int jbase = c * CSZ;

  const int p = qg * 256 + threadIdx.x;
  const float4 q = src[p];

  unsigned bk[SCAP];
#pragma unroll
  for (int i = 0; i < SCAP; ++i) bk[i] = 0xFFFFFFFFu;

  for (int j = 0; j < CSZ; j += 4) {
    float4 c0 = ch[j], c1 = ch[j + 1], c2 = ch[j + 2], c3 = ch[j + 3];
    float m0 = md_of(q, c0);
    float m1 = md_of(q, c1);
    float m2 = md_of(q, c2);
    float m3 = md_of(q, c3);
    insu(bk, key_of(m0, jbase + j));
    insu(bk, key_of(m1, jbase + j + 1));
    insu(bk, key_of(m2, jbase + j + 2));
    insu(bk, key_of(m3, jbase + j + 3));
  }

  const size_t g = (size_t)(t * BB + b) * PP + p;
#pragma unroll
  for (int r = 0; r < SCAP; ++r)
    keys[(size_t)(c * SCAP + r) * NQ + g] = bk[r];
}

// ---------------------------------------------------------------------------
// Kernel G: select. Per query: 48 coalesced key loads (all valid — each
// chunk has 1024 >= 12 real candidates, so no padding ever survives), 48
// independent unrolled cand4 gathers (L2-hot 64 KB slice), exact f32 md
// recompute, order-independent lexicographic stable top-10, disp_var.
// No runtime loop bounds, no divergent fallbacks (r10-r12 post-mortems).
// ---------------------------------------------------------------------------
__global__ __launch_bounds__(256) void knn_select(
    const float4* __restrict__ cand4, const float* __restrict__ pts4,
    const unsigned* __restrict__ keys, int* __restrict__ idx_out,
    float* __restrict__ dv_out) {
  const int g = blockIdx.x * 256 + threadIdx.x;
  const int t = g >> 14;
  const int rem = g & (BP - 1);
  const int b = rem >> 12;
  const int p = rem & (PP - 1);
  const float4* __restrict__ src = cand4 + ((size_t)(b * TT + t) * PP);
  const float4* __restrict__ src1 =
      (const float4*)pts4 + ((size_t)(b * TT + t + 1) * PP);

  const float4 q = src[p];

  float v[KK];
  int vi[KK];
#pragma unroll
  for (int i = 0; i < KK; ++i) { v[i] = INFINITY; vi[i] = 0x7FFFFFFF; }

#pragma unroll
  for (int c = 0; c < CHUNKS; ++c) {
#pragma unroll
    for (int r = 0; r < SCAP; ++r) {
      unsigned k = keys[(size_t)(c * SCAP + r) * NQ + g];
      int j = (int)(k & 0xFFFu);
      float mdv = md_of(q, src[j]);
      insl(v, vi, mdv, j);
    }
  }

  // disp_var over the 10 selected, in rank order (matches top_k order)
  float4 a1 = src1[p];
  const float dqx = a1.x - q.x, dqy = a1.y - q.y, dqz = a1.z - q.z;
  float s = 0.0f;
  int* myidx = idx_out + (size_t)g * KK;
#pragma unroll
  for (int r = 0; r < KK; ++r) {
    int j = vi[r];
    float4 cc = src[j];
    float4 n1 = src1[j];
    float dx = (n1.x - cc.x) - dqx;
    float dy = (n1.y - cc.y) - dqy;
    float dz = (n1.z - cc.z) - dqz;
    s += fmaf(dx, dx, fmaf(dy, dy, dz * dz));
    myidx[r] = j;
  }
  dv_out[g] = s * (1.0f / KK);
}

// ---------------------------------------------------------------------------
// Kernel B2: transpose encoded[b][d][t*P+p] -> featT[t][b][p][d]  (t < NT)
// ---------------------------------------------------------------------------
__global__ __launch_bounds__(256) void transpose_kernel(
    const float* __restrict__ encoded, float* __restrict__ featT) {
  __shared__ float tile[32][33];
  const int slice = blockIdx.z;  // t*BB + b
  const int t = slice / BB, b = slice % BB;
  const int p0 = blockIdx.x * 32, d0 = blockIdx.y * 32;
  const int tx = threadIdx.x, ty = threadIdx.y;
#pragma unroll
  for (int r = 0; r < 4; ++r) {
    int d = d0 + ty + r * 8;
    tile[ty + r * 8][tx] =
        encoded[((size_t)(b * DD + d)) * (TT * PP) + (size_t)t * PP + p0 + tx];
  }
  __syncthreads();
#pragma unroll
  for (int r = 0; r < 4; ++r) {
    int p = p0 + ty + r * 8;
    featT[((size_t)slice * PP + p) * DD + d0 + tx] = tile[tx][ty + r * 8];
  }
}

// ---------------------------------------------------------------------------
// Kernel N: per-point feature L2 norms (wave per point)
// ---------------------------------------------------------------------------
__global__ __launch_bounds__(256) void norms_kernel(
    const float* __restrict__ featT, float* __restrict__ norms) {
  const int w = threadIdx.x >> 6, lane = threadIdx.x & 63;
  const int wid = blockIdx.x * 4 + w;
  for (int i = 0; i < 32; ++i) {
    const int g = wid * 32 + i;
    float2 f = *(const float2*)(featT + (size_t)g * DD + lane * 2);
    float part = fmaf(f.x, f.x, f.y * f.y);
#pragma unroll
    for (int o = 32; o > 0; o >>= 1) part += __shfl_xor(part, o);
    if (lane == 0) norms[g] = sqrtf(part);
  }
}

// ---------------------------------------------------------------------------
// Kernel C: exact lower-median per t via 4-pass radix select on float bits
// ---------------------------------------------------------------------------
__global__ __launch_bounds__(256) void median_kernel(
    const float* __restrict__ disp_var, float* __restrict__ scale) {
  const int t = blockIdx.x;
  const unsigned* u = (const unsigned*)(disp_var + (size_t)t * BP);
  __shared__ unsigned hist[256];
  __shared__ unsigned sh_prefix;
  __shared__ int sh_rank;
  if (threadIdx.x == 0) { sh_prefix = 0u; sh_rank = (BP - 1) >> 1; }
  __syncthreads();
  for (int pass = 0; pass < 4; ++pass) {
    const int shift = 24 - pass * 8;
    hist[threadIdx.x] = 0u;
    __syncthreads();
    const unsigned hmask = (pass == 0) ? 0u : (0xFFFFFFFFu << (shift + 8));
    const unsigned prefix = sh_prefix;
    for (int i = threadIdx.x; i < BP; i += 256) {
      unsigned v = u[i];
      if ((v & hmask) == prefix) atomicAdd(&hist[(v >> shift) & 255u], 1u);
    }
    __syncthreads();
    if (threadIdx.x == 0) {
      int rank = sh_rank;
      unsigned run = 0u;
      for (int c = 0; c < 256; ++c) {
        unsigned h = hist[c];
        if (run + h > (unsigned)rank) {
          sh_rank = rank - (int)run;
          sh_prefix = prefix | ((unsigned)c << shift);
          break;
        }
        run += h;
      }
    }
    __syncthreads();
  }
  if (threadIdx.x == 0) {
    float med = __uint_as_float(sh_prefix);
    scale[t] = fmaxf(med, 1e-6f);
  }
}

// ---------------------------------------------------------------------------
// Kernel D: cosine similarity + rigidity loss, deterministic block partials
// ---------------------------------------------------------------------------
__global__ __launch_bounds__(256) void cos_loss_kernel(
    const float* __restrict__ featT, const int* __restrict__ idxw,
    const float* __restrict__ norms, const float* __restrict__ dv,
    const float* __restrict__ scale, float* __restrict__ partial) {
  const int w = threadIdx.x >> 6, lane = threadIdx.x & 63;
  __shared__ float wsum[4];
  float acc = 0.0f;
  const int qbase = blockIdx.x * QPB + w * (QPB / 4);
  for (int i = 0; i < QPB / 4; ++i) {
    const int g = qbase + i;
    const int t = g >> 14;
    const int p = g & (PP - 1);
    const int slice = g - p;  // base of this (t,b) slice
    const float* fbase = featT + (size_t)g * DD;
    float2 fq = *(const float2*)(fbase + lane * 2);
    float nq = fmaxf(norms[g], 1e-8f);
    const int* ip = idxw + (size_t)g * KK;
    float msum = 0.0f;
#pragma unroll
    for (int k = 0; k < KK; ++k) {
      int j = ip[k];
      const float* nb = featT + (size_t)(slice + j) * DD;
      float2 fn = *(const float2*)(nb + lane * 2);
      float part = fmaf(fq.x, fn.x, fq.y * fn.y);
#pragma unroll
      for (int o = 32; o > 0; o >>= 1) part += __shfl_xor(part, o);
      float nn = fmaxf(norms[slice + j], 1e-8f);
      msum += part / (nq * nn);
    }
    float mean_sim = msum * (1.0f / KK);
    float rig = expf(-dv[g] / scale[t]);
    acc += rig * (1.0f - mean_sim);
  }
  if (lane == 0) wsum[w] = acc;
  __syncthreads();
  if (threadIdx.x == 0)
    partial[blockIdx.x] = (wsum[0] + wsum[1]) + (wsum[2] + wsum[3]);
}

// ---------------------------------------------------------------------------
// Kernel E: final deterministic reduce -> scalar loss
// ---------------------------------------------------------------------------
__global__ __launch_bounds__(256) void final_reduce_kernel(
    const float* __restrict__ partial, float* __restrict__ out) {
  __shared__ float sh[256];
  float s = 0.0f;
  for (int i = threadIdx.x; i < NBLK_COS; i += 256) s += partial[i];
  sh[threadIdx.x] = s;
  __syncthreads();
  for (int st = 128; st > 0; st >>= 1) {
    if (threadIdx.x < st) sh[threadIdx.x] += sh[threadIdx.x + st];
    __syncthreads();
  }
  if (threadIdx.x == 0) out[0] = sh[0] * (1.0f / (float)NQ);
}

extern "C" void kernel_launch(void* const* d_in, const int* in_sizes, int n_in,
                              void* d_out, int out_size, void* d_ws,
                              size_t ws_size, hipStream_t stream) {
  const float* encoded = (const float*)d_in[0];
  const float* pts4 = (const float*)d_in[1];
  char* ws = (char*)d_ws;
  float* featT = (float*)(ws + OFF_FEATT);
  unsigned* keys = (unsigned*)(ws + OFF_KEYS);   // aliases featT (consumed 1st)
  float4* cand4 = (float4*)(ws + OFF_CAND4);     // aliases featT (consumed 1st)
  int* idxw = (int*)(ws + OFF_IDX);
  float* dv = (float*)(ws + OFF_DV);
  float* norms = (float*)(ws + OFF_NORM);
  float* scale = (float*)(ws + OFF_SCALE);
  float* partial = (float*)(ws + OFF_PART);
  float* outp = (float*)d_out;

  prep_cand<<<(BB * TT * PP) / 256, 256, 0, stream>>>(pts4, cand4);
  knn_scan<<<dim3(16 * CHUNKS, BB, NT), 256, 0, stream>>>(cand4, keys);
  knn_select<<<NQ / 256, 256, 0, stream>>>(cand4, pts4, keys, idxw, dv);
  transpose_kernel<<<dim3(PP / 32, DD / 32, NT * BB), dim3(32, 8), 0, stream>>>(
      encoded, featT);
  norms_kernel<<<NBLK_COS, 256, 0, stream>>>(featT, norms);
  median_kernel<<<NT, 256, 0, stream>>>(dv, scale);
  cos_loss_kernel<<<NBLK_COS, 256, 0, stream>>>(featT, idxw, norms, dv, scale,
                                                partial);
  final_reduce_kernel<<<1, 256, 0, stream>>>(partial, outp);
}

// Round 15
// 836.378 us; speedup vs baseline: 1.3382x; 1.0035x over previous
//
#include <hip/hip_runtime.h>
#include <math.h>

// Problem constants (fixed by setup_inputs: B=4, D=128, T=8, P=4096)
#define BB 4
#define DD 128
#define TT 8
#define PP 4096
#define KK 10
#define NT 7              // T-1 frame pairs
#define BP (BB*PP)        // 16384 points per frame across batch
#define NQ (NT*BP)        // 114688 total queries
#define NBLK_COS 896
#define QPB 128           // queries per block in cos kernel (NBLK_COS*QPB == NQ)

#define CHUNKS 4
#define CSZ (PP/CHUNKS)   // 1024 candidates per chunk
#define SCAP 12           // keys kept per chunk (10 + 2 slack for bucket ties)

// Workspace layout (bytes). keys + cand4 alias the featT region (58.7 MB)
// and are fully consumed by knn_select BEFORE transpose_kernel writes featT
// (same-stream ordering).
#define OFF_FEATT 0u                 // NQ*DD floats  = 58,720,256 B
#define OFF_KEYS  0u                 // CHUNKS*SCAP*NQ u32 = 22,020,096 B
#define OFF_CAND4 22020096u          // BB*TT*PP float4 = 2,097,152 B (ends 24.1 MB)
#define OFF_IDX   58720256u          // NQ*KK ints    =  4,587,520 B
#define OFF_DV    63307776u          // NQ floats     =    458,752 B
#define OFF_NORM  63766528u          // NQ floats     =    458,752 B
#define OFF_SCALE 64225280u          // NT floats (padded to 256)
#define OFF_PART  64225536u          // NBLK_COS floats

// md = |q-c|^2 computed as (xx_q + xx_c) - 2*inner. Identical expression in
// every kernel (bit-identical md values). Self-distance is exactly 0.
__device__ __forceinline__ float md_of(const float4 q, const float4 c) {
  float s = q.w + c.w;
  float inner = fmaf(q.x, c.x, fmaf(q.y, c.y, q.z * c.z));
  return fmaf(-2.0f, inner, s);
}

// Sortable u32 key: (f32 bits of md, low 12 bits truncated) | j.
// For non-negative floats, bit order == value order and truncation is
// monotone non-decreasing, so u32 key order == (md-bucket asc, j asc) —
// jax.lax.top_k's tie rule within ~2^-12 relative buckets. fmaxf clamps
// hypothetical tiny-negative rounding results. Select recomputes exact f32
// md, so only CONTAINMENT of the true top-10 in the kept 4x12 is needed
// (2-slot slack per chunk).
__device__ __forceinline__ unsigned key_of(float md, int j) {
  unsigned b = __float_as_uint(fmaxf(md, 0.0f));
  return (b & 0xFFFFF000u) | (unsigned)j;  // j < 4096 fits 12 bits
}

// Branchless keep-SCAP-smallest u32 ladder: compiler emits v_min_u32 /
// v_max_u32 for these ternaries (verified r13 ~= r14 with explicit asm).
__device__ __forceinline__ void insu(unsigned (&bk)[SCAP], unsigned k) {
  bk[SCAP - 1] = bk[SCAP - 1] < k ? bk[SCAP - 1] : k;
#pragma unroll
  for (int i = SCAP - 1; i > 0; --i) {
    unsigned a = bk[i - 1], b = bk[i];
    unsigned lo = a < b ? a : b;
    unsigned hi = a < b ? b : a;
    bk[i - 1] = lo;
    bk[i] = hi;
  }
}

// Exact stable lexicographic (md, idx) keep-10-smallest insert. Fully
// order-independent (ties broken by smaller idx), so insertion order of the
// 48 survivors does not matter. Matches jax.lax.top_k set AND order.
__device__ __forceinline__ void insl(float (&v)[KK], int (&vi)[KK], float md,
                                     int j) {
  bool en = (md < v[KK - 1]) || (md == v[KK - 1] && j < vi[KK - 1]);
  v[KK - 1] = en ? md : v[KK - 1];
  vi[KK - 1] = en ? j : vi[KK - 1];
#pragma unroll
  for (int i = KK - 1; i > 0; --i) {
    bool sw = (v[i] < v[i - 1]) || (v[i] == v[i - 1] && vi[i] < vi[i - 1]);
    float tv = sw ? v[i - 1] : v[i];
    v[i - 1] = sw ? v[i] : v[i - 1];
    v[i] = tv;
    int ti = sw ? vi[i - 1] : vi[i];
    vi[i - 1] = sw ? vi[i] : vi[i - 1];
    vi[i] = ti;
  }
}

// ---------------------------------------------------------------------------
// Kernel P: precompute (x,y,z,xx) per point.
// ---------------------------------------------------------------------------
__global__ __launch_bounds__(256) void prep_cand(
    const float* __restrict__ pts4, float4* __restrict__ cand4) {
  const int i = blockIdx.x * 256 + threadIdx.x;  // over BB*TT*PP
  float4 v = ((const float4*)pts4)[i];
  v.w = fmaf(v.x, v.x, fmaf(v.y, v.y, v.z * v.z));
  cand4[i] = v;
}

// ---------------------------------------------------------------------------
// Kernel S: one-pass chunked KNN scan, thread per query, u32 index-carrying
// ladder. __launch_bounds__(256, 4): r14 post-mortem — default budget
// allocated only 16 VGPRs (bk[12]+q+temps need ~28), forcing the ladder
// arrays into AGPRs with shuttle overhead (~65 VALU/cand measured vs ~31
// intended). 4 waves/SIMD min == measured occupancy, budget 128 VGPRs.
// ---------------------------------------------------------------------------
__global__ __launch_bounds__(256, 4) void knn_scan(
    const float4* __restrict__ cand4, unsigned* __restrict__ keys) {
  const int qg = blockIdx.x >> 2;  // query group 0..15
  const int c = blockIdx.x & 3;    // chunk 0..3
  const int b = blockIdx.y, t = blockIdx.z;
  const float4* __restrict__ src = cand4 + ((size_t)(b * TT + t) * PP);
  const float4* __restrict__ ch = src + c * CSZ;
  const int jbase = c * CSZ;

  const int p = qg * 256 + threadIdx.x;
  const float4 q = src[p];

  unsigned bk[SCAP];
#pragma unroll
  for (int i = 0; i < SCAP; ++i) bk[i] = 0xFFFFFFFFu;

  for (int j = 0; j < CSZ; j += 4) {
    float4 c0 = ch[j], c1 = ch[j + 1], c2 = ch[j + 2], c3 = ch[j + 3];
    float m0 = md_of(q, c0);
    float m1 = md_of(q, c1);
    float m2 = md_of(q, c2);
    float m3 = md_of(q, c3);
    insu(bk, key_of(m0, jbase + j));
    insu(bk, key_of(m1, jbase + j + 1));
    insu(bk, key_of(m2, jbase + j + 2));
    insu(bk, key_of(m3, jbase + j + 3));
  }

  const size_t g = (size_t)(t * BB + b) * PP + p;
#pragma unroll
  for (int r = 0; r < SCAP; ++r)
    keys[(size_t)(c * SCAP + r) * NQ + g] = bk[r];
}

// ---------------------------------------------------------------------------
// Kernel G: select. Per query: 48 coalesced key loads (all valid — each
// chunk has 1024 >= 12 real candidates, so no padding ever survives), 48
// independent unrolled cand4 gathers (L2-hot 64 KB slice), exact f32 md
// recompute, order-independent lexicographic stable top-10, disp_var.
// ---------------------------------------------------------------------------
__global__ __launch_bounds__(256, 4) void knn_select(
    const float4* __restrict__ cand4, const float* __restrict__ pts4,
    const unsigned* __restrict__ keys, int* __restrict__ idx_out,
    float* __restrict__ dv_out) {
  const int g = blockIdx.x * 256 + threadIdx.x;
  const int t = g >> 14;
  const int rem = g & (BP - 1);
  const int b = rem >> 12;
  const int p = rem & (PP - 1);
  const float4* __restrict__ src = cand4 + ((size_t)(b * TT + t) * PP);
  const float4* __restrict__ src1 =
      (const float4*)pts4 + ((size_t)(b * TT + t + 1) * PP);

  const float4 q = src[p];

  float v[KK];
  int vi[KK];
#pragma unroll
  for (int i = 0; i < KK; ++i) { v[i] = INFINITY; vi[i] = 0x7FFFFFFF; }

#pragma unroll
  for (int c = 0; c < CHUNKS; ++c) {
#pragma unroll
    for (int r = 0; r < SCAP; ++r) {
      unsigned k = keys[(size_t)(c * SCAP + r) * NQ + g];
      int j = (int)(k & 0xFFFu);
      float mdv = md_of(q, src[j]);
      insl(v, vi, mdv, j);
    }
  }

  // disp_var over the 10 selected, in rank order (matches top_k order)
  float4 a1 = src1[p];
  const float dqx = a1.x - q.x, dqy = a1.y - q.y, dqz = a1.z - q.z;
  float s = 0.0f;
  int* myidx = idx_out + (size_t)g * KK;
#pragma unroll
  for (int r = 0; r < KK; ++r) {
    int j = vi[r];
    float4 cc = src[j];
    float4 n1 = src1[j];
    float dx = (n1.x - cc.x) - dqx;
    float dy = (n1.y - cc.y) - dqy;
    float dz = (n1.z - cc.z) - dqz;
    s += fmaf(dx, dx, fmaf(dy, dy, dz * dz));
    myidx[r] = j;
  }
  dv_out[g] = s * (1.0f / KK);
}

// ---------------------------------------------------------------------------
// Kernel B2: transpose encoded[b][d][t*P+p] -> featT[t][b][p][d]  (t < NT)
// ---------------------------------------------------------------------------
__global__ __launch_bounds__(256) void transpose_kernel(
    const float* __restrict__ encoded, float* __restrict__ featT) {
  __shared__ float tile[32][33];
  const int slice = blockIdx.z;  // t*BB + b
  const int t = slice / BB, b = slice % BB;
  const int p0 = blockIdx.x * 32, d0 = blockIdx.y * 32;
  const int tx = threadIdx.x, ty = threadIdx.y;
#pragma unroll
  for (int r = 0; r < 4; ++r) {
    int d = d0 + ty + r * 8;
    tile[ty + r * 8][tx] =
        encoded[((size_t)(b * DD + d)) * (TT * PP) + (size_t)t * PP + p0 + tx];
  }
  __syncthreads();
#pragma unroll
  for (int r = 0; r < 4; ++r) {
    int p = p0 + ty + r * 8;
    featT[((size_t)slice * PP + p) * DD + d0 + tx] = tile[tx][ty + r * 8];
  }
}

// ---------------------------------------------------------------------------
// Kernel N: per-point feature L2 norms (wave per point)
// ---------------------------------------------------------------------------
__global__ __launch_bounds__(256) void norms_kernel(
    const float* __restrict__ featT, float* __restrict__ norms) {
  const int w = threadIdx.x >> 6, lane = threadIdx.x & 63;
  const int wid = blockIdx.x * 4 + w;
  for (int i = 0; i < 32; ++i) {
    const int g = wid * 32 + i;
    float2 f = *(const float2*)(featT + (size_t)g * DD + lane * 2);
    float part = fmaf(f.x, f.x, f.y * f.y);
#pragma unroll
    for (int o = 32; o > 0; o >>= 1) part += __shfl_xor(part, o);
    if (lane == 0) norms[g] = sqrtf(part);
  }
}

// ---------------------------------------------------------------------------
// Kernel C: exact lower-median per t via 4-pass radix select on float bits
// ---------------------------------------------------------------------------
__global__ __launch_bounds__(256) void median_kernel(
    const float* __restrict__ disp_var, float* __restrict__ scale) {
  const int t = blockIdx.x;
  const unsigned* u = (const unsigned*)(disp_var + (size_t)t * BP);
  __shared__ unsigned hist[256];
  __shared__ unsigned sh_prefix;
  __shared__ int sh_rank;
  if (threadIdx.x == 0) { sh_prefix = 0u; sh_rank = (BP - 1) >> 1; }
  __syncthreads();
  for (int pass = 0; pass < 4; ++pass) {
    const int shift = 24 - pass * 8;
    hist[threadIdx.x] = 0u;
    __syncthreads();
    const unsigned hmask = (pass == 0) ? 0u : (0xFFFFFFFFu << (shift + 8));
    const unsigned prefix = sh_prefix;
    for (int i = threadIdx.x; i < BP; i += 256) {
      unsigned v = u[i];
      if ((v & hmask) == prefix) atomicAdd(&hist[(v >> shift) & 255u], 1u);
    }
    __syncthreads();
    if (threadIdx.x == 0) {
      int rank = sh_rank;
      unsigned run = 0u;
      for (int c = 0; c < 256; ++c) {
        unsigned h = hist[c];
        if (run + h > (unsigned)rank) {
          sh_rank = rank - (int)run;
          sh_prefix = prefix | ((unsigned)c << shift);
          break;
        }
        run += h;
      }
    }
    __syncthreads();
  }
  if (threadIdx.x == 0) {
    float med = __uint_as_float(sh_prefix);
    scale[t] = fmaxf(med, 1e-6f);
  }
}

// ---------------------------------------------------------------------------
// Kernel D: cosine similarity + rigidity loss, deterministic block partials
// ---------------------------------------------------------------------------
__global__ __launch_bounds__(256) void cos_loss_kernel(
    const float* __restrict__ featT, const int* __restrict__ idxw,
    const float* __restrict__ norms, const float* __restrict__ dv,
    const float* __restrict__ scale, float* __restrict__ partial) {
  const int w = threadIdx.x >> 6, lane = threadIdx.x & 63;
  __shared__ float wsum[4];
  float acc = 0.0f;
  const int qbase = blockIdx.x * QPB + w * (QPB / 4);
  for (int i = 0; i < QPB / 4; ++i) {
    const int g = qbase + i;
    const int t = g >> 14;
    const int p = g & (PP - 1);
    const int slice = g - p;  // base of this (t,b) slice
    const float* fbase = featT + (size_t)g * DD;
    float2 fq = *(const float2*)(fbase + lane * 2);
    float nq = fmaxf(norms[g], 1e-8f);
    const int* ip = idxw + (size_t)g * KK;
    float msum = 0.0f;
#pragma unroll
    for (int k = 0; k < KK; ++k) {
      int j = ip[k];
      const float* nb = featT + (size_t)(slice + j) * DD;
      float2 fn = *(const float2*)(nb + lane * 2);
      float part = fmaf(fq.x, fn.x, fq.y * fn.y);
#pragma unroll
      for (int o = 32; o > 0; o >>= 1) part += __shfl_xor(part, o);
      float nn = fmaxf(norms[slice + j], 1e-8f);
      msum += part / (nq * nn);
    }
    float mean_sim = msum * (1.0f / KK);
    float rig = expf(-dv[g] / scale[t]);
    acc += rig * (1.0f - mean_sim);
  }
  if (lane == 0) wsum[w] = acc;
  __syncthreads();
  if (threadIdx.x == 0)
    partial[blockIdx.x] = (wsum[0] + wsum[1]) + (wsum[2] + wsum[3]);
}

// ---------------------------------------------------------------------------
// Kernel E: final deterministic reduce -> scalar loss
// ---------------------------------------------------------------------------
__global__ __launch_bounds__(256) void final_reduce_kernel(
    const float* __restrict__ partial, float* __restrict__ out) {
  __shared__ float sh[256];
  float s = 0.0f;
  for (int i = threadIdx.x; i < NBLK_COS; i += 256) s += partial[i];
  sh[threadIdx.x] = s;
  __syncthreads();
  for (int st = 128; st > 0; st >>= 1) {
    if (threadIdx.x < st) sh[threadIdx.x] += sh[threadIdx.x + st];
    __syncthreads();
  }
  if (threadIdx.x == 0) out[0] = sh[0] * (1.0f / (float)NQ);
}

extern "C" void kernel_launch(void* const* d_in, const int* in_sizes, int n_in,
                              void* d_out, int out_size, void* d_ws,
                              size_t ws_size, hipStream_t stream) {
  const float* encoded = (const float*)d_in[0];
  const float* pts4 = (const float*)d_in[1];
  char* ws = (char*)d_ws;
  float* featT = (float*)(ws + OFF_FEATT);
  unsigned* keys = (unsigned*)(ws + OFF_KEYS);   // aliases featT (consumed 1st)
  float4* cand4 = (float4*)(ws + OFF_CAND4);     // aliases featT (consumed 1st)
  int* idxw = (int*)(ws + OFF_IDX);
  float* dv = (float*)(ws + OFF_DV);
  float* norms = (float*)(ws + OFF_NORM);
  float* scale = (float*)(ws + OFF_SCALE);
  float* partial = (float*)(ws + OFF_PART);
  float* outp = (float*)d_out;

  prep_cand<<<(BB * TT * PP) / 256, 256, 0, stream>>>(pts4, cand4);
  knn_scan<<<dim3(16 * CHUNKS, BB, NT), 256, 0, stream>>>(cand4, keys);
  knn_select<<<NQ / 256, 256, 0, stream>>>(cand4, pts4, keys, idxw, dv);
  transpose_kernel<<<dim3(PP / 32, DD / 32, NT * BB), dim3(32, 8), 0, stream>>>(
      encoded, featT);
  norms_kernel<<<NBLK_COS, 256, 0, stream>>>(featT, norms);
  median_kernel<<<NT, 256, 0, stream>>>(dv, scale);
  cos_loss_kernel<<<NBLK_COS, 256, 0, stream>>>(featT, idxw, norms, dv, scale,
                                                partial);
  final_reduce_kernel<<<1, 256, 0, stream>>>(partial, outp);
}

// Round 16
// 700.031 us; speedup vs baseline: 1.5988x; 1.1948x over previous
//
#include <hip/hip_runtime.h>
#include <math.h>

// Problem constants (fixed by setup_inputs: B=4, D=128, T=8, P=4096)
#define BB 4
#define DD 128
#define TT 8
#define PP 4096
#define KK 10
#define NT 7              // T-1 frame pairs
#define BP (BB*PP)        // 16384 points per frame across batch
#define NQ (NT*BP)        // 114688 total queries
#define NBLK_COS 896
#define QPB 128           // queries per block in cos kernel (NBLK_COS*QPB == NQ)

#define CHUNKS 4
#define CSZ (PP/CHUNKS)   // 1024 candidates per chunk
#define SCAP 12           // keys kept per chunk (10 + 2 slack for bucket ties)

// Workspace layout (bytes). keys + cand4 alias the featT region (58.7 MB)
// and are fully consumed by knn_select BEFORE transpose_kernel writes featT
// (same-stream ordering).
#define OFF_FEATT 0u                 // NQ*DD floats  = 58,720,256 B
#define OFF_KEYS  0u                 // CHUNKS*SCAP*NQ u32 = 22,020,096 B
#define OFF_CAND4 22020096u          // BB*TT*PP float4 = 2,097,152 B (ends 24.1 MB)
#define OFF_IDX   58720256u          // NQ*KK ints    =  4,587,520 B
#define OFF_DV    63307776u          // NQ floats     =    458,752 B
#define OFF_NORM  63766528u          // NQ floats     =    458,752 B
#define OFF_SCALE 64225280u          // NT floats (padded to 256)
#define OFF_PART  64225536u          // NBLK_COS floats

// Single-instruction 3-input median (VOP3, native on gfx9+). The sorted-
// insert closed form: inserting k into ascending s[0..11] (drop max) is
//   s'[0] = min(s[0], k);  s'[i] = med3(s[i-1], s[i], k)  for i >= 1
// — 12 independent ops (vs ~34 for the compare-exchange bubble after
// clang's cmp+2*cndmask pair expansion; r13-r15 post-mortems).
__device__ __forceinline__ unsigned umed3_(unsigned a, unsigned b, unsigned c) {
  unsigned d;
  asm("v_med3_u32 %0, %1, %2, %3" : "=v"(d) : "v"(a), "v"(b), "v"(c));
  return d;
}

// md = |q-c|^2 computed as (xx_q + xx_c) - 2*inner. Identical expression in
// every kernel (bit-identical md values). Self-distance is exactly 0.
__device__ __forceinline__ float md_of(const float4 q, const float4 c) {
  float s = q.w + c.w;
  float inner = fmaf(q.x, c.x, fmaf(q.y, c.y, q.z * c.z));
  return fmaf(-2.0f, inner, s);
}

// Sortable u32 key: (f32 bits of md, low 12 bits truncated) | j.
// For non-negative floats, bit order == value order and truncation is
// monotone non-decreasing, so u32 key order == (md-bucket asc, j asc) —
// jax.lax.top_k's tie rule within ~2^-12 relative buckets. fmaxf clamps
// hypothetical tiny-negative rounding results. Select recomputes exact f32
// md, so only CONTAINMENT of the true top-10 in the kept 4x12 is needed
// (2-slot slack per chunk).
__device__ __forceinline__ unsigned key_of(float md, int j) {
  unsigned b = __float_as_uint(fmaxf(md, 0.0f));
  return (b & 0xFFFFF000u) | (unsigned)j;  // j < 4096 fits 12 bits
}

// Keep-12-smallest via the med3 insert network. Descending iteration keeps
// every read on the OLD values (bk[i-1] not yet overwritten). Semantics
// identical to the compare-exchange ladder: same kept set, same order.
__device__ __forceinline__ void insu(unsigned (&bk)[SCAP], unsigned k) {
  unsigned nb0 = bk[0] < k ? bk[0] : k;  // v_min_u32
#pragma unroll
  for (int i = SCAP - 1; i > 0; --i)
    bk[i] = umed3_(bk[i - 1], bk[i], k);
  bk[0] = nb0;
}

// Exact stable lexicographic (md, idx) keep-10-smallest insert. Fully
// order-independent (ties broken by smaller idx), so insertion order of the
// 48 survivors does not matter. Matches jax.lax.top_k set AND order.
__device__ __forceinline__ void insl(float (&v)[KK], int (&vi)[KK], float md,
                                     int j) {
  bool en = (md < v[KK - 1]) || (md == v[KK - 1] && j < vi[KK - 1]);
  v[KK - 1] = en ? md : v[KK - 1];
  vi[KK - 1] = en ? j : vi[KK - 1];
#pragma unroll
  for (int i = KK - 1; i > 0; --i) {
    bool sw = (v[i] < v[i - 1]) || (v[i] == v[i - 1] && vi[i] < vi[i - 1]);
    float tv = sw ? v[i - 1] : v[i];
    v[i - 1] = sw ? v[i] : v[i - 1];
    v[i] = tv;
    int ti = sw ? vi[i - 1] : vi[i];
    vi[i - 1] = sw ? vi[i] : vi[i - 1];
    vi[i] = ti;
  }
}

// ---------------------------------------------------------------------------
// Kernel P: precompute (x,y,z,xx) per point.
// ---------------------------------------------------------------------------
__global__ __launch_bounds__(256) void prep_cand(
    const float* __restrict__ pts4, float4* __restrict__ cand4) {
  const int i = blockIdx.x * 256 + threadIdx.x;  // over BB*TT*PP
  float4 v = ((const float4*)pts4)[i];
  v.w = fmaf(v.x, v.x, fmaf(v.y, v.y, v.z * v.z));
  cand4[i] = v;
}

// ---------------------------------------------------------------------------
// Kernel S: one-pass chunked KNN scan, thread per query, u32 index-carrying
// med3-insert ladder. No LDS, no branches in the hot loop.
// ---------------------------------------------------------------------------
__global__ __launch_bounds__(256, 4) void knn_scan(
    const float4* __restrict__ cand4, unsigned* __restrict__ keys) {
  const int qg = blockIdx.x >> 2;  // query group 0..15
  const int c = blockIdx.x & 3;    // chunk 0..3
  const int b = blockIdx.y, t = blockIdx.z;
  const float4* __restrict__ src = cand4 + ((size_t)(b * TT + t) * PP);
  const float4* __restrict__ ch = src + c * CSZ;
  const int jbase = c * CSZ;

  const int p = qg * 256 + threadIdx.x;
  const float4 q = src[p];

  unsigned bk[SCAP];
#pragma unroll
  for (int i = 0; i < SCAP; ++i) bk[i] = 0xFFFFFFFFu;

  for (int j = 0; j < CSZ; j += 4) {
    float4 c0 = ch[j], c1 = ch[j + 1], c2 = ch[j + 2], c3 = ch[j + 3];
    float m0 = md_of(q, c0);
    float m1 = md_of(q, c1);
    float m2 = md_of(q, c2);
    float m3 = md_of(q, c3);
    insu(bk, key_of(m0, jbase + j));
    insu(bk, key_of(m1, jbase + j + 1));
    insu(bk, key_of(m2, jbase + j + 2));
    insu(bk, key_of(m3, jbase + j + 3));
  }

  const size_t g = (size_t)(t * BB + b) * PP + p;
#pragma unroll
  for (int r = 0; r < SCAP; ++r)
    keys[(size_t)(c * SCAP + r) * NQ + g] = bk[r];
}

// ---------------------------------------------------------------------------
// Kernel G: select. Per query: 48 coalesced key loads (all valid — each
// chunk has 1024 >= 12 real candidates, so no padding ever survives), 48
// independent unrolled cand4 gathers (L2-hot 64 KB slice), exact f32 md
// recompute, order-independent lexicographic stable top-10, disp_var.
// ---------------------------------------------------------------------------
__global__ __launch_bounds__(256, 4) void knn_select(
    const float4* __restrict__ cand4, const float* __restrict__ pts4,
    const unsigned* __restrict__ keys, int* __restrict__ idx_out,
    float* __restrict__ dv_out) {
  const int g = blockIdx.x * 256 + threadIdx.x;
  const int t = g >> 14;
  const int rem = g & (BP - 1);
  const int b = rem >> 12;
  const int p = rem & (PP - 1);
  const float4* __restrict__ src = cand4 + ((size_t)(b * TT + t) * PP);
  const float4* __restrict__ src1 =
      (const float4*)pts4 + ((size_t)(b * TT + t + 1) * PP);

  const float4 q = src[p];

  float v[KK];
  int vi[KK];
#pragma unroll
  for (int i = 0; i < KK; ++i) { v[i] = INFINITY; vi[i] = 0x7FFFFFFF; }

#pragma unroll
  for (int c = 0; c < CHUNKS; ++c) {
#pragma unroll
    for (int r = 0; r < SCAP; ++r) {
      unsigned k = keys[(size_t)(c * SCAP + r) * NQ + g];
      int j = (int)(k & 0xFFFu);
      float mdv = md_of(q, src[j]);
      insl(v, vi, mdv, j);
    }
  }

  // disp_var over the 10 selected, in rank order (matches top_k order)
  float4 a1 = src1[p];
  const float dqx = a1.x - q.x, dqy = a1.y - q.y, dqz = a1.z - q.z;
  float s = 0.0f;
  int* myidx = idx_out + (size_t)g * KK;
#pragma unroll
  for (int r = 0; r < KK; ++r) {
    int j = vi[r];
    float4 cc = src[j];
    float4 n1 = src1[j];
    float dx = (n1.x - cc.x) - dqx;
    float dy = (n1.y - cc.y) - dqy;
    float dz = (n1.z - cc.z) - dqz;
    s += fmaf(dx, dx, fmaf(dy, dy, dz * dz));
    myidx[r] = j;
  }
  dv_out[g] = s * (1.0f / KK);
}

// ---------------------------------------------------------------------------
// Kernel B2: transpose encoded[b][d][t*P+p] -> featT[t][b][p][d]  (t < NT)
// ---------------------------------------------------------------------------
__global__ __launch_bounds__(256) void transpose_kernel(
    const float* __restrict__ encoded, float* __restrict__ featT) {
  __shared__ float tile[32][33];
  const int slice = blockIdx.z;  // t*BB + b
  const int t = slice / BB, b = slice % BB;
  const int p0 = blockIdx.x * 32, d0 = blockIdx.y * 32;
  const int tx = threadIdx.x, ty = threadIdx.y;
#pragma unroll
  for (int r = 0; r < 4; ++r) {
    int d = d0 + ty + r * 8;
    tile[ty + r * 8][tx] =
        encoded[((size_t)(b * DD + d)) * (TT * PP) + (size_t)t * PP + p0 + tx];
  }
  __syncthreads();
#pragma unroll
  for (int r = 0; r < 4; ++r) {
    int p = p0 + ty + r * 8;
    featT[((size_t)slice * PP + p) * DD + d0 + tx] = tile[tx][ty + r * 8];
  }
}

// ---------------------------------------------------------------------------
// Kernel N: per-point feature L2 norms (wave per point)
// ---------------------------------------------------------------------------
__global__ __launch_bounds__(256) void norms_kernel(
    const float* __restrict__ featT, float* __restrict__ norms) {
  const int w = threadIdx.x >> 6, lane = threadIdx.x & 63;
  const int wid = blockIdx.x * 4 + w;
  for (int i = 0; i < 32; ++i) {
    const int g = wid * 32 + i;
    float2 f = *(const float2*)(featT + (size_t)g * DD + lane * 2);
    float part = fmaf(f.x, f.x, f.y * f.y);
#pragma unroll
    for (int o = 32; o > 0; o >>= 1) part += __shfl_xor(part, o);
    if (lane == 0) norms[g] = sqrtf(part);
  }
}

// ---------------------------------------------------------------------------
// Kernel C: exact lower-median per t via 4-pass radix select on float bits
// ---------------------------------------------------------------------------
__global__ __launch_bounds__(256) void median_kernel(
    const float* __restrict__ disp_var, float* __restrict__ scale) {
  const int t = blockIdx.x;
  const unsigned* u = (const unsigned*)(disp_var + (size_t)t * BP);
  __shared__ unsigned hist[256];
  __shared__ unsigned sh_prefix;
  __shared__ int sh_rank;
  if (threadIdx.x == 0) { sh_prefix = 0u; sh_rank = (BP - 1) >> 1; }
  __syncthreads();
  for (int pass = 0; pass < 4; ++pass) {
    const int shift = 24 - pass * 8;
    hist[threadIdx.x] = 0u;
    __syncthreads();
    const unsigned hmask = (pass == 0) ? 0u : (0xFFFFFFFFu << (shift + 8));
    const unsigned prefix = sh_prefix;
    for (int i = threadIdx.x; i < BP; i += 256) {
      unsigned v = u[i];
      if ((v & hmask) == prefix) atomicAdd(&hist[(v >> shift) & 255u], 1u);
    }
    __syncthreads();
    if (threadIdx.x == 0) {
      int rank = sh_rank;
      unsigned run = 0u;
      for (int c = 0; c < 256; ++c) {
        unsigned h = hist[c];
        if (run + h > (unsigned)rank) {
          sh_rank = rank - (int)run;
          sh_prefix = prefix | ((unsigned)c << shift);
          break;
        }
        run += h;
      }
    }
    __syncthreads();
  }
  if (threadIdx.x == 0) {
    float med = __uint_as_float(sh_prefix);
    scale[t] = fmaxf(med, 1e-6f);
  }
}

// ---------------------------------------------------------------------------
// Kernel D: cosine similarity + rigidity loss, deterministic block partials
// ---------------------------------------------------------------------------
__global__ __launch_bounds__(256) void cos_loss_kernel(
    const float* __restrict__ featT, const int* __restrict__ idxw,
    const float* __restrict__ norms, const float* __restrict__ dv,
    const float* __restrict__ scale, float* __restrict__ partial) {
  const int w = threadIdx.x >> 6, lane = threadIdx.x & 63;
  __shared__ float wsum[4];
  float acc = 0.0f;
  const int qbase = blockIdx.x * QPB + w * (QPB / 4);
  for (int i = 0; i < QPB / 4; ++i) {
    const int g = qbase + i;
    const int t = g >> 14;
    const int p = g & (PP - 1);
    const int slice = g - p;  // base of this (t,b) slice
    const float* fbase = featT + (size_t)g * DD;
    float2 fq = *(const float2*)(fbase + lane * 2);
    float nq = fmaxf(norms[g], 1e-8f);
    const int* ip = idxw + (size_t)g * KK;
    float msum = 0.0f;
#pragma unroll
    for (int k = 0; k < KK; ++k) {
      int j = ip[k];
      const float* nb = featT + (size_t)(slice + j) * DD;
      float2 fn = *(const float2*)(nb + lane * 2);
      float part = fmaf(fq.x, fn.x, fq.y * fn.y);
#pragma unroll
      for (int o = 32; o > 0; o >>= 1) part += __shfl_xor(part, o);
      float nn = fmaxf(norms[slice + j], 1e-8f);
      msum += part / (nq * nn);
    }
    float mean_sim = msum * (1.0f / KK);
    float rig = expf(-dv[g] / scale[t]);
    acc += rig * (1.0f - mean_sim);
  }
  if (lane == 0) wsum[w] = acc;
  __syncthreads();
  if (threadIdx.x == 0)
    partial[blockIdx.x] = (wsum[0] + wsum[1]) + (wsum[2] + wsum[3]);
}

// ---------------------------------------------------------------------------
// Kernel E: final deterministic reduce -> scalar loss
// ---------------------------------------------------------------------------
__global__ __launch_bounds__(256) void final_reduce_kernel(
    const float* __restrict__ partial, float* __restrict__ out) {
  __shared__ float sh[256];
  float s = 0.0f;
  for (int i = threadIdx.x; i < NBLK_COS; i += 256) s += partial[i];
  sh[threadIdx.x] = s;
  __syncthreads();
  for (int st = 128; st > 0; st >>= 1) {
    if (threadIdx.x < st) sh[threadIdx.x] += sh[threadIdx.x + st];
    __syncthreads();
  }
  if (threadIdx.x == 0) out[0] = sh[0] * (1.0f / (float)NQ);
}

extern "C" void kernel_launch(void* const* d_in, const int* in_sizes, int n_in,
                              void* d_out, int out_size, void* d_ws,
                              size_t ws_size, hipStream_t stream) {
  const float* encoded = (const float*)d_in[0];
  const float* pts4 = (const float*)d_in[1];
  char* ws = (char*)d_ws;
  float* featT = (float*)(ws + OFF_FEATT);
  unsigned* keys = (unsigned*)(ws + OFF_KEYS);   // aliases featT (consumed 1st)
  float4* cand4 = (float4*)(ws + OFF_CAND4);     // aliases featT (consumed 1st)
  int* idxw = (int*)(ws + OFF_IDX);
  float* dv = (float*)(ws + OFF_DV);
  float* norms = (float*)(ws + OFF_NORM);
  float* scale = (float*)(ws + OFF_SCALE);
  float* partial = (float*)(ws + OFF_PART);
  float* outp = (float*)d_out;

  prep_cand<<<(BB * TT * PP) / 256, 256, 0, stream>>>(pts4, cand4);
  knn_scan<<<dim3(16 * CHUNKS, BB, NT), 256, 0, stream>>>(cand4, keys);
  knn_select<<<NQ / 256, 256, 0, stream>>>(cand4, pts4, keys, idxw, dv);
  transpose_kernel<<<dim3(PP / 32, DD / 32, NT * BB), dim3(32, 8), 0, stream>>>(
      encoded, featT);
  norms_kernel<<<NBLK_COS, 256, 0, stream>>>(featT, norms);
  median_kernel<<<NT, 256, 0, stream>>>(dv, scale);
  cos_loss_kernel<<<NBLK_COS, 256, 0, stream>>>(featT, idxw, norms, dv, scale,
                                                partial);
  final_reduce_kernel<<<1, 256, 0, stream>>>(partial, outp);
}

// Round 17
// 695.506 us; speedup vs baseline: 1.6092x; 1.0065x over previous
//
#include <hip/hip_runtime.h>
#include <math.h>

// Problem constants (fixed by setup_inputs: B=4, D=128, T=8, P=4096)
#define BB 4
#define DD 128
#define TT 8
#define PP 4096
#define KK 10
#define NT 7              // T-1 frame pairs
#define BP (BB*PP)        // 16384 points per frame across batch
#define NQ (NT*BP)        // 114688 total queries
#define NBLK_COS 896
#define QPB 128           // queries per block in cos kernel (NBLK_COS*QPB == NQ)

#define CHUNKS 4
#define CSZ (PP/CHUNKS)   // 1024 candidates per chunk
#define SCAP 12           // keys kept per chunk (10 + 2 slack for bucket ties)

// Workspace layout (bytes). keys + cand4 alias the featT region (58.7 MB)
// and are fully consumed by knn_select4 BEFORE transpose_kernel writes featT
// (same-stream ordering).
#define OFF_FEATT 0u                 // NQ*DD floats  = 58,720,256 B
#define OFF_KEYS  0u                 // CHUNKS*SCAP*NQ u32 = 22,020,096 B
#define OFF_CAND4 22020096u          // BB*TT*PP float4 = 2,097,152 B (ends 24.1 MB)
#define OFF_IDX   58720256u          // NQ*KK ints    =  4,587,520 B
#define OFF_DV    63307776u          // NQ floats     =    458,752 B
#define OFF_NORM  63766528u          // NQ floats     =    458,752 B
#define OFF_SCALE 64225280u          // NT floats (padded to 256)
#define OFF_PART  64225536u          // NBLK_COS floats

// Single-instruction 3-input median (VOP3, native on gfx9+). Sorted-insert
// closed form: inserting k into ascending s[0..11] (drop max) is
//   s'[0] = min(s[0], k);  s'[i] = med3(s[i-1], s[i], k)  for i >= 1
// — 12 independent ops (r16: scan 402 -> ~240 us with this).
__device__ __forceinline__ unsigned umed3_(unsigned a, unsigned b, unsigned c) {
  unsigned d;
  asm("v_med3_u32 %0, %1, %2, %3" : "=v"(d) : "v"(a), "v"(b), "v"(c));
  return d;
}

// md = |q-c|^2 computed as (xx_q + xx_c) - 2*inner. Identical expression in
// every kernel (bit-identical md values). Self-distance is exactly 0.
__device__ __forceinline__ float md_of(const float4 q, const float4 c) {
  float s = q.w + c.w;
  float inner = fmaf(q.x, c.x, fmaf(q.y, c.y, q.z * c.z));
  return fmaf(-2.0f, inner, s);
}

// Sortable u32 key: (f32 bits of md, low 12 bits truncated) | j.
// For non-negative floats, bit order == value order and truncation is
// monotone non-decreasing, so u32 key order == (md-bucket asc, j asc).
// Select recomputes exact f32 md, so only CONTAINMENT of the true top-10 in
// the kept 4x12 is needed (2-slot slack per chunk).
__device__ __forceinline__ unsigned key_of(float md, int j) {
  unsigned b = __float_as_uint(fmaxf(md, 0.0f));
  return (b & 0xFFFFF000u) | (unsigned)j;  // j < 4096 fits 12 bits
}

// Keep-12-smallest via the med3 insert network. Descending iteration keeps
// every read on the OLD values.
__device__ __forceinline__ void insu(unsigned (&bk)[SCAP], unsigned k) {
  unsigned nb0 = bk[0] < k ? bk[0] : k;  // v_min_u32
#pragma unroll
  for (int i = SCAP - 1; i > 0; --i)
    bk[i] = umed3_(bk[i - 1], bk[i], k);
  bk[0] = nb0;
}

// Exact stable lexicographic (md, idx) keep-10-smallest insert. Fully
// order-independent (ties broken by smaller idx), so insertion order of the
// 48 survivors does not matter. Matches jax.lax.top_k set AND order.
__device__ __forceinline__ void insl(float (&v)[KK], int (&vi)[KK], float md,
                                     int j) {
  bool en = (md < v[KK - 1]) || (md == v[KK - 1] && j < vi[KK - 1]);
  v[KK - 1] = en ? md : v[KK - 1];
  vi[KK - 1] = en ? j : vi[KK - 1];
#pragma unroll
  for (int i = KK - 1; i > 0; --i) {
    bool sw = (v[i] < v[i - 1]) || (v[i] == v[i - 1] && vi[i] < vi[i - 1]);
    float tv = sw ? v[i - 1] : v[i];
    v[i - 1] = sw ? v[i] : v[i - 1];
    v[i] = tv;
    int ti = sw ? vi[i - 1] : vi[i];
    vi[i - 1] = sw ? vi[i] : vi[i - 1];
    vi[i] = ti;
  }
}

// ---------------------------------------------------------------------------
// Kernel P: precompute (x,y,z,xx) per point.
// ---------------------------------------------------------------------------
__global__ __launch_bounds__(256) void prep_cand(
    const float* __restrict__ pts4, float4* __restrict__ cand4) {
  const int i = blockIdx.x * 256 + threadIdx.x;  // over BB*TT*PP
  float4 v = ((const float4*)pts4)[i];
  v.w = fmaf(v.x, v.x, fmaf(v.y, v.y, v.z * v.z));
  cand4[i] = v;
}

// ---------------------------------------------------------------------------
// Kernel S: one-pass chunked KNN scan, thread per query, u32 index-carrying
// med3-insert ladder. No LDS, no branches in the hot loop.
// ---------------------------------------------------------------------------
__global__ __launch_bounds__(256, 4) void knn_scan(
    const float4* __restrict__ cand4, unsigned* __restrict__ keys) {
  const int qg = blockIdx.x >> 2;  // query group 0..15
  const int c = blockIdx.x & 3;    // chunk 0..3
  const int b = blockIdx.y, t = blockIdx.z;
  const float4* __restrict__ src = cand4 + ((size_t)(b * TT + t) * PP);
  const float4* __restrict__ ch = src + c * CSZ;
  const int jbase = c * CSZ;

  const int p = qg * 256 + threadIdx.x;
  const float4 q = src[p];

  unsigned bk[SCAP];
#pragma unroll
  for (int i = 0; i < SCAP; ++i) bk[i] = 0xFFFFFFFFu;

  for (int j = 0; j < CSZ; j += 4) {
    float4 c0 = ch[j], c1 = ch[j + 1], c2 = ch[j + 2], c3 = ch[j + 3];
    float m0 = md_of(q, c0);
    float m1 = md_of(q, c1);
    float m2 = md_of(q, c2);
    float m3 = md_of(q, c3);
    insu(bk, key_of(m0, jbase + j));
    insu(bk, key_of(m1, jbase + j + 1));
    insu(bk, key_of(m2, jbase + j + 2));
    insu(bk, key_of(m3, jbase + j + 3));
  }

  const size_t g = (size_t)(t * BB + b) * PP + p;
#pragma unroll
  for (int r = 0; r < SCAP; ++r)
    keys[(size_t)(c * SCAP + r) * NQ + g] = bk[r];
}

// ---------------------------------------------------------------------------
// Kernel G: select, 4-waves-per-query-group (r16 post-mortem: thread-per-
// query caps ANY such kernel at 1792 waves = 1.75/SIMD; select's 48-gather
// latency chain can't be hidden -> 304 us at 17% VALUBusy).
// Block = 256 thr = 4 waves x 64 queries. Wave w handles chunk w:
//   Phase A (7168 waves): 12 coalesced key loads (lane = query), 12 L2-hot
//     cand4 gathers, exact f32 md, (md,idx) -> LDS. No ladder, max MLP.
//   Phase B (wave 0 only): merge 48 LDS entries via order-independent insl,
//     then the BYTE-IDENTICAL r16 epilogue (rank-order disp_var + writes) —
//     output bit-identical to r13-r16 (absmax 0.0).
// ---------------------------------------------------------------------------
__global__ __launch_bounds__(256) void knn_select4(
    const float4* __restrict__ cand4, const float* __restrict__ pts4,
    const unsigned* __restrict__ keys, int* __restrict__ idx_out,
    float* __restrict__ dv_out) {
  __shared__ float lmd[CHUNKS][64][SCAP + 1];          // stride 13 -> no conflicts
  __shared__ unsigned short lix[CHUNKS][64][SCAP + 1];
  const int w = threadIdx.x >> 6;   // wave == chunk
  const int ql = threadIdx.x & 63;  // query within block
  const int g = blockIdx.x * 64 + ql;
  const int t = g >> 14;
  const int rem = g & (BP - 1);
  const int b = rem >> 12;
  const int p = rem & (PP - 1);
  const float4* __restrict__ src = cand4 + ((size_t)(b * TT + t) * PP);
  const float4* __restrict__ src1 =
      (const float4*)pts4 + ((size_t)(b * TT + t + 1) * PP);

  const float4 q = src[p];

  // ---- Phase A: chunk w's 12 survivors -> exact (md, idx) in LDS
#pragma unroll
  for (int r = 0; r < SCAP; ++r) {
    unsigned k = keys[(size_t)(w * SCAP + r) * NQ + g];
    int j = (int)(k & 0xFFFu);
    float mdv = md_of(q, src[j]);
    lmd[w][ql][r] = mdv;
    lix[w][ql][r] = (unsigned short)j;
  }
  __syncthreads();

  // ---- Phase B: wave 0 merges + epilogue (identical to r16 select)
  if (w != 0) return;

  float v[KK];
  int vi[KK];
#pragma unroll
  for (int i = 0; i < KK; ++i) { v[i] = INFINITY; vi[i] = 0x7FFFFFFF; }

#pragma unroll
  for (int c = 0; c < CHUNKS; ++c) {
#pragma unroll
    for (int r = 0; r < SCAP; ++r)
      insl(v, vi, lmd[c][ql][r], (int)lix[c][ql][r]);
  }

  // disp_var over the 10 selected, in rank order (matches top_k order)
  float4 a1 = src1[p];
  const float dqx = a1.x - q.x, dqy = a1.y - q.y, dqz = a1.z - q.z;
  float s = 0.0f;
  int* myidx = idx_out + (size_t)g * KK;
#pragma unroll
  for (int r = 0; r < KK; ++r) {
    int j = vi[r];
    float4 cc = src[j];
    float4 n1 = src1[j];
    float dx = (n1.x - cc.x) - dqx;
    float dy = (n1.y - cc.y) - dqy;
    float dz = (n1.z - cc.z) - dqz;
    s += fmaf(dx, dx, fmaf(dy, dy, dz * dz));
    myidx[r] = j;
  }
  dv_out[g] = s * (1.0f / KK);
}

// ---------------------------------------------------------------------------
// Kernel B2: transpose encoded[b][d][t*P+p] -> featT[t][b][p][d]  (t < NT)
// ---------------------------------------------------------------------------
__global__ __launch_bounds__(256) void transpose_kernel(
    const float* __restrict__ encoded, float* __restrict__ featT) {
  __shared__ float tile[32][33];
  const int slice = blockIdx.z;  // t*BB + b
  const int t = slice / BB, b = slice % BB;
  const int p0 = blockIdx.x * 32, d0 = blockIdx.y * 32;
  const int tx = threadIdx.x, ty = threadIdx.y;
#pragma unroll
  for (int r = 0; r < 4; ++r) {
    int d = d0 + ty + r * 8;
    tile[ty + r * 8][tx] =
        encoded[((size_t)(b * DD + d)) * (TT * PP) + (size_t)t * PP + p0 + tx];
  }
  __syncthreads();
#pragma unroll
  for (int r = 0; r < 4; ++r) {
    int p = p0 + ty + r * 8;
    featT[((size_t)slice * PP + p) * DD + d0 + tx] = tile[tx][ty + r * 8];
  }
}

// ---------------------------------------------------------------------------
// Kernel N: per-point feature L2 norms (wave per point)
// ---------------------------------------------------------------------------
__global__ __launch_bounds__(256) void norms_kernel(
    const float* __restrict__ featT, float* __restrict__ norms) {
  const int w = threadIdx.x >> 6, lane = threadIdx.x & 63;
  const int wid = blockIdx.x * 4 + w;
  for (int i = 0; i < 32; ++i) {
    const int g = wid * 32 + i;
    float2 f = *(const float2*)(featT + (size_t)g * DD + lane * 2);
    float part = fmaf(f.x, f.x, f.y * f.y);
#pragma unroll
    for (int o = 32; o > 0; o >>= 1) part += __shfl_xor(part, o);
    if (lane == 0) norms[g] = sqrtf(part);
  }
}

// ---------------------------------------------------------------------------
// Kernel C: exact lower-median per t via 4-pass radix select on float bits
// ---------------------------------------------------------------------------
__global__ __launch_bounds__(256) void median_kernel(
    const float* __restrict__ disp_var, float* __restrict__ scale) {
  const int t = blockIdx.x;
  const unsigned* u = (const unsigned*)(disp_var + (size_t)t * BP);
  __shared__ unsigned hist[256];
  __shared__ unsigned sh_prefix;
  __shared__ int sh_rank;
  if (threadIdx.x == 0) { sh_prefix = 0u; sh_rank = (BP - 1) >> 1; }
  __syncthreads();
  for (int pass = 0; pass < 4; ++pass) {
    const int shift = 24 - pass * 8;
    hist[threadIdx.x] = 0u;
    __syncthreads();
    const unsigned hmask = (pass == 0) ? 0u : (0xFFFFFFFFu << (shift + 8));
    const unsigned prefix = sh_prefix;
    for (int i = threadIdx.x; i < BP; i += 256) {
      unsigned v = u[i];
      if ((v & hmask) == prefix) atomicAdd(&hist[(v >> shift) & 255u], 1u);
    }
    __syncthreads();
    if (threadIdx.x == 0) {
      int rank = sh_rank;
      unsigned run = 0u;
      for (int c = 0; c < 256; ++c) {
        unsigned h = hist[c];
        if (run + h > (unsigned)rank) {
          sh_rank = rank - (int)run;
          sh_prefix = prefix | ((unsigned)c << shift);
          break;
        }
        run += h;
      }
    }
    __syncthreads();
  }
  if (threadIdx.x == 0) {
    float med = __uint_as_float(sh_prefix);
    scale[t] = fmaxf(med, 1e-6f);
  }
}

// ---------------------------------------------------------------------------
// Kernel D: cosine similarity + rigidity loss, deterministic block partials
// ---------------------------------------------------------------------------
__global__ __launch_bounds__(256) void cos_loss_kernel(
    const float* __restrict__ featT, const int* __restrict__ idxw,
    const float* __restrict__ norms, const float* __restrict__ dv,
    const float* __restrict__ scale, float* __restrict__ partial) {
  const int w = threadIdx.x >> 6, lane = threadIdx.x & 63;
  __shared__ float wsum[4];
  float acc = 0.0f;
  const int qbase = blockIdx.x * QPB + w * (QPB / 4);
  for (int i = 0; i < QPB / 4; ++i) {
    const int g = qbase + i;
    const int t = g >> 14;
    const int p = g & (PP - 1);
    const int slice = g - p;  // base of this (t,b) slice
    const float* fbase = featT + (size_t)g * DD;
    float2 fq = *(const float2*)(fbase + lane * 2);
    float nq = fmaxf(norms[g], 1e-8f);
    const int* ip = idxw + (size_t)g * KK;
    float msum = 0.0f;
#pragma unroll
    for (int k = 0; k < KK; ++k) {
      int j = ip[k];
      const float* nb = featT + (size_t)(slice + j) * DD;
      float2 fn = *(const float2*)(nb + lane * 2);
      float part = fmaf(fq.x, fn.x, fq.y * fn.y);
#pragma unroll
      for (int o = 32; o > 0; o >>= 1) part += __shfl_xor(part, o);
      float nn = fmaxf(norms[slice + j], 1e-8f);
      msum += part / (nq * nn);
    }
    float mean_sim = msum * (1.0f / KK);
    float rig = expf(-dv[g] / scale[t]);
    acc += rig * (1.0f - mean_sim);
  }
  if (lane == 0) wsum[w] = acc;
  __syncthreads();
  if (threadIdx.x == 0)
    partial[blockIdx.x] = (wsum[0] + wsum[1]) + (wsum[2] + wsum[3]);
}

// ---------------------------------------------------------------------------
// Kernel E: final deterministic reduce -> scalar loss
// ---------------------------------------------------------------------------
__global__ __launch_bounds__(256) void final_reduce_kernel(
    const float* __restrict__ partial, float* __restrict__ out) {
  __shared__ float sh[256];
  float s = 0.0f;
  for (int i = threadIdx.x; i < NBLK_COS; i += 256) s += partial[i];
  sh[threadIdx.x] = s;
  __syncthreads();
  for (int st = 128; st > 0; st >>= 1) {
    if (threadIdx.x < st) sh[threadIdx.x] += sh[threadIdx.x + st];
    __syncthreads();
  }
  if (threadIdx.x == 0) out[0] = sh[0] * (1.0f / (float)NQ);
}

extern "C" void kernel_launch(void* const* d_in, const int* in_sizes, int n_in,
                              void* d_out, int out_size, void* d_ws,
                              size_t ws_size, hipStream_t stream) {
  const float* encoded = (const float*)d_in[0];
  const float* pts4 = (const float*)d_in[1];
  char* ws = (char*)d_ws;
  float* featT = (float*)(ws + OFF_FEATT);
  unsigned* keys = (unsigned*)(ws + OFF_KEYS);   // aliases featT (consumed 1st)
  float4* cand4 = (float4*)(ws + OFF_CAND4);     // aliases featT (consumed 1st)
  int* idxw = (int*)(ws + OFF_IDX);
  float* dv = (float*)(ws + OFF_DV);
  float* norms = (float*)(ws + OFF_NORM);
  float* scale = (float*)(ws + OFF_SCALE);
  float* partial = (float*)(ws + OFF_PART);
  float* outp = (float*)d_out;

  prep_cand<<<(BB * TT * PP) / 256, 256, 0, stream>>>(pts4, cand4);
  knn_scan<<<dim3(16 * CHUNKS, BB, NT), 256, 0, stream>>>(cand4, keys);
  knn_select4<<<NQ / 64, 256, 0, stream>>>(cand4, pts4, keys, idxw, dv);
  transpose_kernel<<<dim3(PP / 32, DD / 32, NT * BB), dim3(32, 8), 0, stream>>>(
      encoded, featT);
  norms_kernel<<<NBLK_COS, 256, 0, stream>>>(featT, norms);
  median_kernel<<<NT, 256, 0, stream>>>(dv, scale);
  cos_loss_kernel<<<NBLK_COS, 256, 0, stream>>>(featT, idxw, norms, dv, scale,
                                                partial);
  final_reduce_kernel<<<1, 256, 0, stream>>>(partial, outp);
}